// Round 2
// baseline (690.722 us; speedup 1.0000x reference)
//
#include <hip/hip_runtime.h>

typedef __bf16 bf16_t;
typedef __bf16 bf16x8 __attribute__((ext_vector_type(8)));
typedef __bf16 bf16x4 __attribute__((ext_vector_type(4)));
typedef float f32x4 __attribute__((ext_vector_type(4)));

#define MFMA16(A_, B_, C_) __builtin_amdgcn_mfma_f32_16x16x32_bf16((A_), (B_), (C_), 0, 0, 0)

__device__ __forceinline__ void gload_lds16(const bf16_t* g, bf16_t* l) {
  __builtin_amdgcn_global_load_lds(
      (const __attribute__((address_space(1))) void*)g,
      (__attribute__((address_space(3))) void*)l, 16, 0, 0);
}

// fp32 -> bf16, 4 elements/thread
__global__ __launch_bounds__(256) void k_convert(const float* __restrict__ in,
                                                 bf16_t* __restrict__ out, int n4) {
  int i = blockIdx.x * 256 + threadIdx.x;
  if (i >= n4) return;
  float4 v = ((const float4*)in)[i];
  bf16x4 o;
  o[0] = (__bf16)v.x; o[1] = (__bf16)v.y; o[2] = (__bf16)v.z; o[3] = (__bf16)v.w;
  *(bf16x4*)(out + (size_t)i * 4) = o;
}

// out[c][r] = (bf16) in[r][c];  in is [R][C] fp32. 64x64 tiles, 256 threads.
__global__ __launch_bounds__(256) void k_transpose(const float* __restrict__ in,
                                                   bf16_t* __restrict__ out, int R, int C) {
  __shared__ float tile[64][65];
  int tx = threadIdx.x & 63;
  int ty = threadIdx.x >> 6;  // 0..3
  int bc = blockIdx.x * 64;
  int br = blockIdx.y * 64;
#pragma unroll
  for (int i = ty; i < 64; i += 4)
    tile[i][tx] = in[(size_t)(br + i) * C + bc + tx];
  __syncthreads();
#pragma unroll
  for (int i = ty; i < 64; i += 4)
    out[(size_t)(bc + i) * R + br + tx] = (bf16_t)tile[tx][i];
}

// block-split row permutation: original token row -> attention-layout row
__device__ __forceinline__ int permrow(int r) {
  int b  = r >> 12;        // batch
  int l  = r & 4095;
  int ix = (l >> 11) & 1;
  int sx = (l >> 6) & 31;
  int iy = (l >> 5) & 1;
  int sy = l & 31;
  return (b << 12) + (ix << 11) + (iy << 10) + (sx << 5) + sy;
}

// C[M][N] = A[M][K] * B^T[N][K], bf16 in, 128x128 tile, BK=64, 4 waves.
// MODE 0: fused QKV (N = 2048 | 512 | 512), bf16 out with row permutation.
// MODE 1: fp32 out, straight rows (N = 2048).
template <int MODE>
__global__ __launch_bounds__(256, 2) void k_gemm(
    const bf16_t* __restrict__ A,
    const bf16_t* __restrict__ B0, const bf16_t* __restrict__ B1,
    const bf16_t* __restrict__ B2,
    bf16_t* __restrict__ Cq, bf16_t* __restrict__ Ck, bf16_t* __restrict__ Cv,
    float* __restrict__ Cf) {
  const int K = 2048;
  int bid = blockIdx.x;
  int tm = bid & 63;   // M/128 = 64
  int tn = bid >> 6;

  const bf16_t* Bp;
  int brow;
  if (MODE == 0) {
    if (tn < 16)      { Bp = B0; brow = tn << 7; }
    else if (tn < 20) { Bp = B1; brow = (tn - 16) << 7; }
    else              { Bp = B2; brow = (tn - 20) << 7; }
  } else {
    Bp = B0; brow = tn << 7;
  }

  __shared__ bf16_t As[128 * 64];
  __shared__ bf16_t Bs[128 * 64];

  int tid = threadIdx.x;
  int lane = tid & 63;
  int w = tid >> 6;
  int wm = w >> 1, wn = w & 1;
  int g16 = lane >> 4, cl = lane & 15;
  int lrow = lane >> 3, lcol = (lane & 7) << 3;

  const bf16_t* ag = A + (size_t)(tm * 128 + w * 32 + lrow) * K + lcol;
  const bf16_t* bg = Bp + (size_t)(brow + w * 32 + lrow) * K + lcol;
  bf16_t* al = As + (w * 32) * 64;
  bf16_t* bl = Bs + (w * 32) * 64;

  f32x4 acc[4][4];
#pragma unroll
  for (int i = 0; i < 4; ++i)
#pragma unroll
    for (int j = 0; j < 4; ++j) acc[i][j] = (f32x4)(0.0f);

  for (int kt = 0; kt < K / 64; ++kt) {
#pragma unroll
    for (int i = 0; i < 4; ++i) {
      gload_lds16(ag + (size_t)i * 8 * K + kt * 64, al + i * 8 * 64);
      gload_lds16(bg + (size_t)i * 8 * K + kt * 64, bl + i * 8 * 64);
    }
    __syncthreads();  // drains vmcnt (global_load_lds) + cross-wave visibility

    bf16x8 af[4][2], bfr[4][2];
#pragma unroll
    for (int mi = 0; mi < 4; ++mi)
#pragma unroll
      for (int kk = 0; kk < 2; ++kk) {
        af[mi][kk]  = *(const bf16x8*)&As[(wm * 64 + mi * 16 + cl) * 64 + kk * 32 + g16 * 8];
        bfr[mi][kk] = *(const bf16x8*)&Bs[(wn * 64 + mi * 16 + cl) * 64 + kk * 32 + g16 * 8];
      }
#pragma unroll
    for (int mi = 0; mi < 4; ++mi)
#pragma unroll
      for (int ni = 0; ni < 4; ++ni)
#pragma unroll
        for (int kk = 0; kk < 2; ++kk)
          acc[mi][ni] = MFMA16(af[mi][kk], bfr[ni][kk], acc[mi][ni]);
    __syncthreads();  // all reads done before next stage overwrites
  }

#pragma unroll
  for (int mi = 0; mi < 4; ++mi) {
#pragma unroll
    for (int rr = 0; rr < 4; ++rr) {
      int r = tm * 128 + wm * 64 + mi * 16 + g16 * 4 + rr;
      if (MODE == 0) {
        int rp = permrow(r);
#pragma unroll
        for (int ni = 0; ni < 4; ++ni) {
          int c = (tn << 7) + wn * 64 + ni * 16 + cl;
          float v = acc[mi][ni][rr];
          if (c < 2048)      Cq[(size_t)rp * 2048 + c] = (bf16_t)v;
          else if (c < 2560) Ck[(size_t)rp * 512 + (c - 2048)] = (bf16_t)v;
          else               Cv[(size_t)rp * 512 + (c - 2560)] = (bf16_t)v;
        }
      } else {
#pragma unroll
        for (int ni = 0; ni < 4; ++ni) {
          int c = (tn << 7) + wn * 64 + ni * 16 + cl;
          Cf[(size_t)r * 2048 + c] = acc[mi][ni][rr];
        }
      }
    }
  }
}

// Flash-style block attention. Grid: qc(8) x h(32) x n(8). WG = 4 waves,
// each wave owns 32 q-rows (128/WG). KV iterated in tiles of 128.
// __launch_bounds__(256, 1): allocator may use up to ~512 VGPRs. The live
// set in the QK phase is ~160-190 VGPRs (s[2][8] f32x4 alone is 64); the
// previous (256,2) bound capped at 128 and spilled ~1 GB/dispatch of
// scratch traffic (rocprof WRITE_SIZE 1.06e9 vs 32 MB ideal). Occupancy is
// LDS-capped at 2 blocks/CU either way, so raising the VGPR budget is free.
__global__ __launch_bounds__(256, 1) void k_attn(
    const bf16_t* __restrict__ Qp, const bf16_t* __restrict__ Kp,
    const bf16_t* __restrict__ Vp, bf16_t* __restrict__ O) {
  int bid = blockIdx.x;
  int qc = bid & 7;
  int h  = (bid >> 3) & 31;
  int n  = bid >> 8;
  int kvh = h >> 2;  // GQA: query head h -> kv head h//4

  __shared__ bf16_t Ks[128 * 72];       // [kv][d], +8 pad
  __shared__ bf16_t Vt[64 * 136];       // [d][kv], XOR-swizzled columns
  __shared__ bf16_t Ps[4 * 32 * 136];   // per-wave P [32][128], stride 136

  int tid = threadIdx.x, lane = tid & 63, w = tid >> 6;
  int g16 = lane >> 4, cl = lane & 15;

  int qrow0 = n * 1024 + qc * 128 + w * 32;
  bf16x8 qf[2][2];
#pragma unroll
  for (int mi = 0; mi < 2; ++mi)
#pragma unroll
    for (int kc = 0; kc < 2; ++kc)
      qf[mi][kc] = *(const bf16x8*)&Qp[(size_t)(qrow0 + mi * 16 + cl) * 2048 +
                                       h * 64 + kc * 32 + g16 * 8];

  f32x4 o_acc[2][4];
  float m_run[2][4], l_run[2][4];
#pragma unroll
  for (int mi = 0; mi < 2; ++mi) {
#pragma unroll
    for (int cf = 0; cf < 4; ++cf) o_acc[mi][cf] = (f32x4)(0.0f);
#pragma unroll
    for (int rr = 0; rr < 4; ++rr) { m_run[mi][rr] = -1e30f; l_run[mi][rr] = 0.0f; }
  }

  bf16_t* Pw = &Ps[w * 32 * 136];
  const float sc = 0.125f;  // D^-0.5

  for (int it = 0; it < 8; ++it) {
    int kvbase = n * 1024 + it * 128;
    __syncthreads();  // previous iteration's LDS reads complete
    // stage K [128][64] (padded rows) and V transposed [64][128] (XOR swizzle)
#pragma unroll
    for (int j = 0; j < 4; ++j) {
      int idx = j * 256 + tid;
      int i = idx >> 3, c = idx & 7;
      const bf16_t* kvsrc = Kp + (size_t)(kvbase + i) * 512 + kvh * 64 + c * 8;
      bf16x8 kv8 = *(const bf16x8*)kvsrc;
      *(bf16x8*)&Ks[i * 72 + c * 8] = kv8;
      const bf16_t* vsrc = Vp + (size_t)(kvbase + i) * 512 + kvh * 64 + c * 8;
      bf16x8 vv8 = *(const bf16x8*)vsrc;
      int isw = i ^ (c << 4);  // bank/bijective column swizzle per 8-row stripe of d
#pragma unroll
      for (int e = 0; e < 8; ++e)
        Vt[(c * 8 + e) * 136 + isw] = vv8[e];
    }
    __syncthreads();

    // S = Q K^T  (per wave: 32 q-rows x 128 kv)
    f32x4 s[2][8];
#pragma unroll
    for (int mi = 0; mi < 2; ++mi)
#pragma unroll
      for (int cb = 0; cb < 8; ++cb) s[mi][cb] = (f32x4)(0.0f);
#pragma unroll
    for (int cb = 0; cb < 8; ++cb) {
      bf16x8 kf0 = *(const bf16x8*)&Ks[(cb * 16 + cl) * 72 + g16 * 8];
      bf16x8 kf1 = *(const bf16x8*)&Ks[(cb * 16 + cl) * 72 + 32 + g16 * 8];
#pragma unroll
      for (int mi = 0; mi < 2; ++mi) {
        s[mi][cb] = MFMA16(qf[mi][0], kf0, s[mi][cb]);
        s[mi][cb] = MFMA16(qf[mi][1], kf1, s[mi][cb]);
      }
    }

    // online softmax: rows live at (g16*4+rr), cols across the 16-lane group
#pragma unroll
    for (int mi = 0; mi < 2; ++mi) {
#pragma unroll
      for (int rr = 0; rr < 4; ++rr) {
        float mx = -1e30f;
#pragma unroll
        for (int cb = 0; cb < 8; ++cb) mx = fmaxf(mx, s[mi][cb][rr]);
        mx *= sc;
#pragma unroll
        for (int off = 1; off < 16; off <<= 1)
          mx = fmaxf(mx, __shfl_xor(mx, off));
        float mold = m_run[mi][rr];
        float mnew = fmaxf(mold, mx);
        float resc = __expf(mold - mnew);
        m_run[mi][rr] = mnew;
        float rsum = 0.0f;
#pragma unroll
        for (int cb = 0; cb < 8; ++cb) {
          float p = __expf(fmaf(sc, s[mi][cb][rr], -mnew));
          s[mi][cb][rr] = p;
          rsum += p;
        }
#pragma unroll
        for (int off = 1; off < 16; off <<= 1)
          rsum += __shfl_xor(rsum, off);
        l_run[mi][rr] = l_run[mi][rr] * resc + rsum;
#pragma unroll
        for (int cf = 0; cf < 4; ++cf) o_acc[mi][cf][rr] *= resc;
      }
    }

    // P -> LDS (bf16), colblock order staggered by lane-group to spread banks
#pragma unroll
    for (int mi = 0; mi < 2; ++mi)
#pragma unroll
      for (int cbx = 0; cbx < 8; ++cbx) {
        int cb = (cbx + g16) & 7;
#pragma unroll
        for (int rr = 0; rr < 4; ++rr)
          Pw[(mi * 16 + g16 * 4 + rr) * 136 + cb * 16 + cl] = (bf16_t)s[mi][cb][rr];
      }
    __syncthreads();

    // O += P V
#pragma unroll
    for (int kc = 0; kc < 4; ++kc) {
      bf16x8 pa0 = *(const bf16x8*)&Pw[cl * 136 + kc * 32 + g16 * 8];
      bf16x8 pa1 = *(const bf16x8*)&Pw[(16 + cl) * 136 + kc * 32 + g16 * 8];
#pragma unroll
      for (int cf = 0; cf < 4; ++cf) {
        int d = cf * 16 + cl;
        int xr = ((d >> 3) & 7) << 4;
        bf16x8 vf = *(const bf16x8*)&Vt[d * 136 + ((kc * 32 + g16 * 8) ^ xr)];
        o_acc[0][cf] = MFMA16(pa0, vf, o_acc[0][cf]);
        o_acc[1][cf] = MFMA16(pa1, vf, o_acc[1][cf]);
      }
    }
  }

  // write O (attention-layout row == GEMM2 row == output token row)
#pragma unroll
  for (int mi = 0; mi < 2; ++mi)
#pragma unroll
    for (int rr = 0; rr < 4; ++rr) {
      float inv = 1.0f / l_run[mi][rr];
      int row = qrow0 + mi * 16 + g16 * 4 + rr;
#pragma unroll
      for (int cf = 0; cf < 4; ++cf)
        O[(size_t)row * 2048 + h * 64 + cf * 16 + cl] =
            (bf16_t)(o_acc[mi][cf][rr] * inv);
    }
}

extern "C" void kernel_launch(void* const* d_in, const int* in_sizes, int n_in,
                              void* d_out, int out_size, void* d_ws, size_t ws_size,
                              hipStream_t stream) {
  const float* X  = (const float*)d_in[0];
  const float* Wq = (const float*)d_in[1];
  const float* Wk = (const float*)d_in[2];
  const float* Wv = (const float*)d_in[3];
  const float* Wo = (const float*)d_in[4];
  float* out = (float*)d_out;

  char* ws = (char*)d_ws;
  const size_t MB = 1024 * 1024;
  bf16_t* Xb  = (bf16_t*)(ws + 0);        // [8192][2048]  32 MB
  bf16_t* WqT = (bf16_t*)(ws + 32 * MB);  // [2048][2048]   8 MB
  bf16_t* WkT = (bf16_t*)(ws + 40 * MB);  // [512][2048]    2 MB
  bf16_t* WvT = (bf16_t*)(ws + 42 * MB);  // [512][2048]    2 MB
  bf16_t* WoT = (bf16_t*)(ws + 44 * MB);  // [2048][2048]   8 MB
  bf16_t* Qp  = (bf16_t*)(ws + 52 * MB);  // [8192][2048]  32 MB (permuted rows)
  bf16_t* Kp  = (bf16_t*)(ws + 84 * MB);  // [8192][512]    8 MB
  bf16_t* Vp  = (bf16_t*)(ws + 92 * MB);  // [8192][512]    8 MB
  bf16_t* Ob  = (bf16_t*)(ws + 100 * MB); // [8192][2048]  32 MB

  k_convert<<<16384, 256, 0, stream>>>(X, Xb, 4194304);
  k_transpose<<<dim3(32, 32), 256, 0, stream>>>(Wq, WqT, 2048, 2048);
  k_transpose<<<dim3(8, 32), 256, 0, stream>>>(Wk, WkT, 2048, 512);
  k_transpose<<<dim3(8, 32), 256, 0, stream>>>(Wv, WvT, 2048, 512);
  k_transpose<<<dim3(32, 32), 256, 0, stream>>>(Wo, WoT, 2048, 2048);

  k_gemm<0><<<1536, 256, 0, stream>>>(Xb, WqT, WkT, WvT, Qp, Kp, Vp, nullptr);
  k_attn<<<2048, 256, 0, stream>>>(Qp, Kp, Vp, Ob);
  k_gemm<1><<<1024, 256, 0, stream>>>(Ob, WoT, nullptr, nullptr, nullptr, nullptr,
                                      nullptr, out);
}

// Round 3
// 445.165 us; speedup vs baseline: 1.5516x; 1.5516x over previous
//
#include <hip/hip_runtime.h>

typedef __bf16 bf16_t;
typedef __bf16 bf16x8 __attribute__((ext_vector_type(8)));
typedef __bf16 bf16x4 __attribute__((ext_vector_type(4)));
typedef float f32x4 __attribute__((ext_vector_type(4)));

#define MFMA16(A_, B_, C_) __builtin_amdgcn_mfma_f32_16x16x32_bf16((A_), (B_), (C_), 0, 0, 0)

__device__ __forceinline__ void gload_lds16(const bf16_t* g, bf16_t* l) {
  __builtin_amdgcn_global_load_lds(
      (const __attribute__((address_space(1))) void*)g,
      (__attribute__((address_space(3))) void*)l, 16, 0, 0);
}

// fp32 -> bf16, 4 elements/thread
__global__ __launch_bounds__(256) void k_convert(const float* __restrict__ in,
                                                 bf16_t* __restrict__ out, int n4) {
  int i = blockIdx.x * 256 + threadIdx.x;
  if (i >= n4) return;
  float4 v = ((const float4*)in)[i];
  bf16x4 o;
  o[0] = (__bf16)v.x; o[1] = (__bf16)v.y; o[2] = (__bf16)v.z; o[3] = (__bf16)v.w;
  *(bf16x4*)(out + (size_t)i * 4) = o;
}

// out[c][r] = (bf16) in[r][c];  in is [R][C] fp32. 64x64 tiles, 256 threads.
__global__ __launch_bounds__(256) void k_transpose(const float* __restrict__ in,
                                                   bf16_t* __restrict__ out, int R, int C) {
  __shared__ float tile[64][65];
  int tx = threadIdx.x & 63;
  int ty = threadIdx.x >> 6;  // 0..3
  int bc = blockIdx.x * 64;
  int br = blockIdx.y * 64;
#pragma unroll
  for (int i = ty; i < 64; i += 4)
    tile[i][tx] = in[(size_t)(br + i) * C + bc + tx];
  __syncthreads();
#pragma unroll
  for (int i = ty; i < 64; i += 4)
    out[(size_t)(bc + i) * R + br + tx] = (bf16_t)tile[tx][i];
}

// block-split row permutation: original token row -> attention-layout row
__device__ __forceinline__ int permrow(int r) {
  int b  = r >> 12;        // batch
  int l  = r & 4095;
  int ix = (l >> 11) & 1;
  int sx = (l >> 6) & 31;
  int iy = (l >> 5) & 1;
  int sy = l & 31;
  return (b << 12) + (ix << 11) + (iy << 10) + (sx << 5) + sy;
}

// C[M][N] = A[M][K] * B^T[N][K], bf16 in, 128x128 tile, BK=64, 4 waves.
// MODE 0: fused QKV (N = 2048 | 512 | 512), bf16 out with row permutation.
// MODE 1: fp32 out, straight rows (N = 2048).
template <int MODE>
__global__ __launch_bounds__(256, 2) void k_gemm(
    const bf16_t* __restrict__ A,
    const bf16_t* __restrict__ B0, const bf16_t* __restrict__ B1,
    const bf16_t* __restrict__ B2,
    bf16_t* __restrict__ Cq, bf16_t* __restrict__ Ck, bf16_t* __restrict__ Cv,
    float* __restrict__ Cf) {
  const int K = 2048;
  int bid = blockIdx.x;
  int tm = bid & 63;   // M/128 = 64
  int tn = bid >> 6;

  const bf16_t* Bp;
  int brow;
  if (MODE == 0) {
    if (tn < 16)      { Bp = B0; brow = tn << 7; }
    else if (tn < 20) { Bp = B1; brow = (tn - 16) << 7; }
    else              { Bp = B2; brow = (tn - 20) << 7; }
  } else {
    Bp = B0; brow = tn << 7;
  }

  __shared__ bf16_t As[128 * 64];
  __shared__ bf16_t Bs[128 * 64];

  int tid = threadIdx.x;
  int lane = tid & 63;
  int w = tid >> 6;
  int wm = w >> 1, wn = w & 1;
  int g16 = lane >> 4, cl = lane & 15;
  int lrow = lane >> 3, lcol = (lane & 7) << 3;

  const bf16_t* ag = A + (size_t)(tm * 128 + w * 32 + lrow) * K + lcol;
  const bf16_t* bg = Bp + (size_t)(brow + w * 32 + lrow) * K + lcol;
  bf16_t* al = As + (w * 32) * 64;
  bf16_t* bl = Bs + (w * 32) * 64;

  f32x4 acc[4][4];
#pragma unroll
  for (int i = 0; i < 4; ++i)
#pragma unroll
    for (int j = 0; j < 4; ++j) acc[i][j] = (f32x4)(0.0f);

  for (int kt = 0; kt < K / 64; ++kt) {
#pragma unroll
    for (int i = 0; i < 4; ++i) {
      gload_lds16(ag + (size_t)i * 8 * K + kt * 64, al + i * 8 * 64);
      gload_lds16(bg + (size_t)i * 8 * K + kt * 64, bl + i * 8 * 64);
    }
    __syncthreads();  // drains vmcnt (global_load_lds) + cross-wave visibility

    bf16x8 af[4][2], bfr[4][2];
#pragma unroll
    for (int mi = 0; mi < 4; ++mi)
#pragma unroll
      for (int kk = 0; kk < 2; ++kk) {
        af[mi][kk]  = *(const bf16x8*)&As[(wm * 64 + mi * 16 + cl) * 64 + kk * 32 + g16 * 8];
        bfr[mi][kk] = *(const bf16x8*)&Bs[(wn * 64 + mi * 16 + cl) * 64 + kk * 32 + g16 * 8];
      }
#pragma unroll
    for (int mi = 0; mi < 4; ++mi)
#pragma unroll
      for (int ni = 0; ni < 4; ++ni)
#pragma unroll
        for (int kk = 0; kk < 2; ++kk)
          acc[mi][ni] = MFMA16(af[mi][kk], bfr[ni][kk], acc[mi][ni]);
    __syncthreads();  // all reads done before next stage overwrites
  }

#pragma unroll
  for (int mi = 0; mi < 4; ++mi) {
#pragma unroll
    for (int rr = 0; rr < 4; ++rr) {
      int r = tm * 128 + wm * 64 + mi * 16 + g16 * 4 + rr;
      if (MODE == 0) {
        int rp = permrow(r);
#pragma unroll
        for (int ni = 0; ni < 4; ++ni) {
          int c = (tn << 7) + wn * 64 + ni * 16 + cl;
          float v = acc[mi][ni][rr];
          if (c < 2048)      Cq[(size_t)rp * 2048 + c] = (bf16_t)v;
          else if (c < 2560) Ck[(size_t)rp * 512 + (c - 2048)] = (bf16_t)v;
          else               Cv[(size_t)rp * 512 + (c - 2560)] = (bf16_t)v;
        }
      } else {
#pragma unroll
        for (int ni = 0; ni < 4; ++ni) {
          int c = (tn << 7) + wn * 64 + ni * 16 + cl;
          Cf[(size_t)r * 2048 + c] = acc[mi][ni][rr];
        }
      }
    }
  }
}

// Flash-style block attention. Grid: qc(8) x h(32) x n(8). WG = 4 waves,
// each wave owns 32 q-rows. KV staged in tiles of 128, PROCESSED IN TWO
// 64-col HALVES so the live S-tile is s[2][4] (32 VGPRs). Peak live set
// ~110 VGPRs -- below the RA's ~112-128 budget, so no scratch spill
// (rounds 1-2 spilled ~1 GB/dispatch; launch_bounds could not fix it).
// Ps is wave-local: P-write -> PV-read needs no __syncthreads (in-order
// per-wave DS pipe). Ks/Ps use the T2 XOR swizzle (col ^= (row&7)<<3,
// same involution on write and read) -> no padding, LDS = 50176 B -> 3
// blocks/CU.
__global__ __launch_bounds__(256, 2) void k_attn(
    const bf16_t* __restrict__ Qp, const bf16_t* __restrict__ Kp,
    const bf16_t* __restrict__ Vp, bf16_t* __restrict__ O) {
  int bid = blockIdx.x;
  int qc = bid & 7;
  int h  = (bid >> 3) & 31;
  int n  = bid >> 8;
  int kvh = h >> 2;  // GQA: query head h -> kv head h//4

  __shared__ bf16_t Ks[128 * 64];      // [kv][d], XOR-swizzled cols
  __shared__ bf16_t Vt[64 * 136];      // [d][kv], column swizzle isw = kv ^ (c<<4)
  __shared__ bf16_t Ps[4 * 32 * 64];   // per-wave P [32 q][64 kv], XOR-swizzled

  int tid = threadIdx.x, lane = tid & 63, w = tid >> 6;
  int g16 = lane >> 4, cl = lane & 15;

  int qrow0 = n * 1024 + qc * 128 + w * 32;
  bf16x8 qf[2][2];
#pragma unroll
  for (int mi = 0; mi < 2; ++mi)
#pragma unroll
    for (int kc = 0; kc < 2; ++kc)
      qf[mi][kc] = *(const bf16x8*)&Qp[(size_t)(qrow0 + mi * 16 + cl) * 2048 +
                                       h * 64 + kc * 32 + g16 * 8];

  f32x4 o_acc[2][4];
  float m_run[2][4], l_run[2][4];
#pragma unroll
  for (int mi = 0; mi < 2; ++mi) {
#pragma unroll
    for (int cf = 0; cf < 4; ++cf) o_acc[mi][cf] = (f32x4)(0.0f);
#pragma unroll
    for (int rr = 0; rr < 4; ++rr) { m_run[mi][rr] = -1e30f; l_run[mi][rr] = 0.0f; }
  }

  bf16_t* Pw = &Ps[w * 32 * 64];
  const float sc = 0.125f;  // D^-0.5

  for (int it = 0; it < 8; ++it) {
    int kvbase = n * 1024 + it * 128;
    __syncthreads();  // previous iteration's Ks/Vt reads complete
    // stage K [128][64] (XOR swizzle) and V transposed [64][128] (col swizzle)
#pragma unroll
    for (int j = 0; j < 4; ++j) {
      int idx = j * 256 + tid;
      int i = idx >> 3, c = idx & 7;
      bf16x8 kv8 = *(const bf16x8*)(Kp + (size_t)(kvbase + i) * 512 + kvh * 64 + c * 8);
      *(bf16x8*)&Ks[i * 64 + ((c ^ (i & 7)) << 3)] = kv8;
      bf16x8 vv8 = *(const bf16x8*)(Vp + (size_t)(kvbase + i) * 512 + kvh * 64 + c * 8);
      int isw = i ^ (c << 4);  // bijective within 128, spreads banks across c
#pragma unroll
      for (int e = 0; e < 8; ++e)
        Vt[(c * 8 + e) * 136 + isw] = vv8[e];
    }
    __syncthreads();

#pragma unroll
    for (int half = 0; half < 2; ++half) {
      int kv0 = half << 6;
      // S = Q K^T for this 64-kv half (s[2][4] keeps live regs low)
      f32x4 s[2][4];
#pragma unroll
      for (int mi = 0; mi < 2; ++mi)
#pragma unroll
        for (int cb = 0; cb < 4; ++cb) s[mi][cb] = (f32x4)(0.0f);
#pragma unroll
      for (int cb = 0; cb < 4; ++cb) {
        int krow = kv0 + cb * 16 + cl;
        int sw = (cl & 7) << 3;  // (krow&7)<<3 == (cl&7)<<3
        bf16x8 kf0 = *(const bf16x8*)&Ks[krow * 64 + ((g16 * 8) ^ sw)];
        bf16x8 kf1 = *(const bf16x8*)&Ks[krow * 64 + ((32 + g16 * 8) ^ sw)];
#pragma unroll
        for (int mi = 0; mi < 2; ++mi) {
          s[mi][cb] = MFMA16(qf[mi][0], kf0, s[mi][cb]);
          s[mi][cb] = MFMA16(qf[mi][1], kf1, s[mi][cb]);
        }
      }

      // online softmax over the 64 cols (row = (mi,g16,rr), cols on 16 lanes)
#pragma unroll
      for (int mi = 0; mi < 2; ++mi) {
#pragma unroll
        for (int rr = 0; rr < 4; ++rr) {
          float mx = fmaxf(fmaxf(s[mi][0][rr], s[mi][1][rr]),
                           fmaxf(s[mi][2][rr], s[mi][3][rr]));
          mx *= sc;
#pragma unroll
          for (int off = 1; off < 16; off <<= 1)
            mx = fmaxf(mx, __shfl_xor(mx, off));
          float mold = m_run[mi][rr];
          float mnew = fmaxf(mold, mx);
          float resc = __expf(mold - mnew);
          m_run[mi][rr] = mnew;
          float rsum = 0.0f;
#pragma unroll
          for (int cb = 0; cb < 4; ++cb) {
            float p = __expf(fmaf(sc, s[mi][cb][rr], -mnew));
            s[mi][cb][rr] = p;
            rsum += p;
          }
#pragma unroll
          for (int off = 1; off < 16; off <<= 1)
            rsum += __shfl_xor(rsum, off);
          l_run[mi][rr] = l_run[mi][rr] * resc + rsum;
#pragma unroll
          for (int cf = 0; cf < 4; ++cf) o_acc[mi][cf][rr] *= resc;
        }
      }

      // P -> Pw (bf16, XOR swizzle). Wave-local: no barrier needed.
#pragma unroll
      for (int mi = 0; mi < 2; ++mi)
#pragma unroll
        for (int cb = 0; cb < 4; ++cb)
#pragma unroll
          for (int rr = 0; rr < 4; ++rr) {
            int prow = mi * 16 + g16 * 4 + rr;
            Pw[prow * 64 + (((cb * 16) + cl) ^ ((prow & 7) << 3))] =
                (bf16_t)s[mi][cb][rr];
          }

      // O += P V for this half (reads wave-local Pw + shared Vt)
#pragma unroll
      for (int kc = 0; kc < 2; ++kc) {
        int psw = (cl & 7) << 3;
        bf16x8 pa0 = *(const bf16x8*)&Pw[cl * 64 + ((kc * 32 + g16 * 8) ^ psw)];
        bf16x8 pa1 = *(const bf16x8*)&Pw[(16 + cl) * 64 + ((kc * 32 + g16 * 8) ^ psw)];
#pragma unroll
        for (int cf = 0; cf < 4; ++cf) {
          int d = cf * 16 + cl;
          int xr = ((d >> 3) & 7) << 4;
          bf16x8 vf = *(const bf16x8*)&Vt[d * 136 + ((kv0 + kc * 32 + g16 * 8) ^ xr)];
          o_acc[0][cf] = MFMA16(pa0, vf, o_acc[0][cf]);
          o_acc[1][cf] = MFMA16(pa1, vf, o_acc[1][cf]);
        }
      }
      // keep half-1 PV reads ordered before half-2 P overwrites
      __builtin_amdgcn_sched_barrier(0);
    }
  }

  // write O (attention-layout row == GEMM2 row == output token row)
#pragma unroll
  for (int mi = 0; mi < 2; ++mi)
#pragma unroll
    for (int rr = 0; rr < 4; ++rr) {
      float inv = 1.0f / l_run[mi][rr];
      int row = qrow0 + mi * 16 + g16 * 4 + rr;
#pragma unroll
      for (int cf = 0; cf < 4; ++cf)
        O[(size_t)row * 2048 + h * 64 + cf * 16 + cl] =
            (bf16_t)(o_acc[mi][cf][rr] * inv);
    }
}

extern "C" void kernel_launch(void* const* d_in, const int* in_sizes, int n_in,
                              void* d_out, int out_size, void* d_ws, size_t ws_size,
                              hipStream_t stream) {
  const float* X  = (const float*)d_in[0];
  const float* Wq = (const float*)d_in[1];
  const float* Wk = (const float*)d_in[2];
  const float* Wv = (const float*)d_in[3];
  const float* Wo = (const float*)d_in[4];
  float* out = (float*)d_out;

  char* ws = (char*)d_ws;
  const size_t MB = 1024 * 1024;
  bf16_t* Xb  = (bf16_t*)(ws + 0);        // [8192][2048]  32 MB
  bf16_t* WqT = (bf16_t*)(ws + 32 * MB);  // [2048][2048]   8 MB
  bf16_t* WkT = (bf16_t*)(ws + 40 * MB);  // [512][2048]    2 MB
  bf16_t* WvT = (bf16_t*)(ws + 42 * MB);  // [512][2048]    2 MB
  bf16_t* WoT = (bf16_t*)(ws + 44 * MB);  // [2048][2048]   8 MB
  bf16_t* Qp  = (bf16_t*)(ws + 52 * MB);  // [8192][2048]  32 MB (permuted rows)
  bf16_t* Kp  = (bf16_t*)(ws + 84 * MB);  // [8192][512]    8 MB
  bf16_t* Vp  = (bf16_t*)(ws + 92 * MB);  // [8192][512]    8 MB
  bf16_t* Ob  = (bf16_t*)(ws + 100 * MB); // [8192][2048]  32 MB

  k_convert<<<16384, 256, 0, stream>>>(X, Xb, 4194304);
  k_transpose<<<dim3(32, 32), 256, 0, stream>>>(Wq, WqT, 2048, 2048);
  k_transpose<<<dim3(8, 32), 256, 0, stream>>>(Wk, WkT, 2048, 512);
  k_transpose<<<dim3(8, 32), 256, 0, stream>>>(Wv, WvT, 2048, 512);
  k_transpose<<<dim3(32, 32), 256, 0, stream>>>(Wo, WoT, 2048, 2048);

  k_gemm<0><<<1536, 256, 0, stream>>>(Xb, WqT, WkT, WvT, Qp, Kp, Vp, nullptr);
  k_attn<<<2048, 256, 0, stream>>>(Qp, Kp, Vp, Ob);
  k_gemm<1><<<1024, 256, 0, stream>>>(Ob, WoT, nullptr, nullptr, nullptr, nullptr,
                                      nullptr, out);
}

// Round 5
// 367.356 us; speedup vs baseline: 1.8803x; 1.2118x over previous
//
#include <hip/hip_runtime.h>

typedef __bf16 bf16_t;
typedef __bf16 bf16x8 __attribute__((ext_vector_type(8)));
typedef __bf16 bf16x4 __attribute__((ext_vector_type(4)));
typedef float f32x4 __attribute__((ext_vector_type(4)));
typedef float f32x16 __attribute__((ext_vector_type(16)));
typedef short s16x4 __attribute__((ext_vector_type(4)));

#define MFMA16(A_, B_, C_) __builtin_amdgcn_mfma_f32_16x16x32_bf16((A_), (B_), (C_), 0, 0, 0)
#define MFMA32(A_, B_, C_) __builtin_amdgcn_mfma_f32_32x32x16_bf16((A_), (B_), (C_), 0, 0, 0)

// softmax scale folded into Q at GEMM0: 0.125 * log2(e) so p = exp2(s - m)
#define QSC 0.18033688011112042f

__device__ __forceinline__ void gload_lds16(const bf16_t* g, bf16_t* l) {
  __builtin_amdgcn_global_load_lds(
      (const __attribute__((address_space(1))) void*)g,
      (__attribute__((address_space(3))) void*)l, 16, 0, 0);
}

__device__ __forceinline__ unsigned cvt_pk_bf16(float a, float b) {
  unsigned r;
  asm("v_cvt_pk_bf16_f32 %0, %1, %2" : "=v"(r) : "v"(a), "v"(b));
  return r;
}

// HW transpose read. Semantics (m156/m162): within each 16-lane group, lane
// l must supply addr = chunk_base + (l&15)*8 BYTES (its own 8B chunk of a
// 128B = 4x16-bf16 row-major tile); the HW redistributes so lane l receives
// column (l&15): elem j = chunk[j][l&15]. Round 4's bug: stride 2B not 8B.
__device__ __forceinline__ s16x4 tr_b16(const bf16_t* p) {
  s16x4 d;
  unsigned off = (unsigned)(size_t)(const __attribute__((address_space(3))) bf16_t*)p;
  asm volatile("ds_read_b64_tr_b16 %0, %1" : "=v"(d) : "v"(off));
  return d;
}

// exchange: ra[l<32]=b[l+32], ra[l>=32]=a ; rb[l<32]=b, rb[l>=32]=a[l-32]
__device__ __forceinline__ void swap32(unsigned a, unsigned b, int hi,
                                       unsigned& ra, unsigned& rb) {
  unsigned bx = (unsigned)__shfl_xor((int)b, 32);
  unsigned ax = (unsigned)__shfl_xor((int)a, 32);
  ra = hi ? a : bx;
  rb = hi ? ax : b;
}

// fp32 -> bf16, 4 elements/thread
__global__ __launch_bounds__(256) void k_convert(const float* __restrict__ in,
                                                 bf16_t* __restrict__ out, int n4) {
  int i = blockIdx.x * 256 + threadIdx.x;
  if (i >= n4) return;
  float4 v = ((const float4*)in)[i];
  bf16x4 o;
  o[0] = (__bf16)v.x; o[1] = (__bf16)v.y; o[2] = (__bf16)v.z; o[3] = (__bf16)v.w;
  *(bf16x4*)(out + (size_t)i * 4) = o;
}

// out[c][r] = (bf16) in[r][c];  in is [R][C] fp32. 64x64 tiles, 256 threads.
__global__ __launch_bounds__(256) void k_transpose(const float* __restrict__ in,
                                                   bf16_t* __restrict__ out, int R, int C) {
  __shared__ float tile[64][65];
  int tx = threadIdx.x & 63;
  int ty = threadIdx.x >> 6;
  int bc = blockIdx.x * 64;
  int br = blockIdx.y * 64;
#pragma unroll
  for (int i = ty; i < 64; i += 4)
    tile[i][tx] = in[(size_t)(br + i) * C + bc + tx];
  __syncthreads();
#pragma unroll
  for (int i = ty; i < 64; i += 4)
    out[(size_t)(bc + i) * R + br + tx] = (bf16_t)tile[tx][i];
}

// block-split row permutation: original token row -> attention-layout row
__device__ __forceinline__ int permrow(int r) {
  int b  = r >> 12;
  int l  = r & 4095;
  int ix = (l >> 11) & 1;
  int sx = (l >> 6) & 31;
  int iy = (l >> 5) & 1;
  int sy = l & 31;
  return (b << 12) + (ix << 11) + (iy << 10) + (sx << 5) + sy;
}

// C[M][N] = A[M][K] * B^T[N][K], bf16 in, 128x128 tile, BK=64, 4 waves.
// MODE 0: fused QKV (N = 2048 | 512 | 512), bf16 out, row-permuted; Q scaled.
// MODE 1: fp32 out, straight rows (N = 2048).
template <int MODE>
__global__ __launch_bounds__(256, 2) void k_gemm(
    const bf16_t* __restrict__ A,
    const bf16_t* __restrict__ B0, const bf16_t* __restrict__ B1,
    const bf16_t* __restrict__ B2,
    bf16_t* __restrict__ Cq, bf16_t* __restrict__ Ck, bf16_t* __restrict__ Cv,
    float* __restrict__ Cf) {
  const int K = 2048;
  int bid = blockIdx.x;
  int tm = bid & 63;
  int tn = bid >> 6;

  const bf16_t* Bp;
  int brow;
  if (MODE == 0) {
    if (tn < 16)      { Bp = B0; brow = tn << 7; }
    else if (tn < 20) { Bp = B1; brow = (tn - 16) << 7; }
    else              { Bp = B2; brow = (tn - 20) << 7; }
  } else {
    Bp = B0; brow = tn << 7;
  }

  __shared__ bf16_t As[128 * 64];
  __shared__ bf16_t Bs[128 * 64];

  int tid = threadIdx.x;
  int lane = tid & 63;
  int w = tid >> 6;
  int wm = w >> 1, wn = w & 1;
  int g16 = lane >> 4, cl = lane & 15;
  int lrow = lane >> 3, lcol = (lane & 7) << 3;

  const bf16_t* ag = A + (size_t)(tm * 128 + w * 32 + lrow) * K + lcol;
  const bf16_t* bg = Bp + (size_t)(brow + w * 32 + lrow) * K + lcol;
  bf16_t* al = As + (w * 32) * 64;
  bf16_t* bl = Bs + (w * 32) * 64;

  f32x4 acc[4][4];
#pragma unroll
  for (int i = 0; i < 4; ++i)
#pragma unroll
    for (int j = 0; j < 4; ++j) acc[i][j] = (f32x4)(0.0f);

  for (int kt = 0; kt < K / 64; ++kt) {
#pragma unroll
    for (int i = 0; i < 4; ++i) {
      gload_lds16(ag + (size_t)i * 8 * K + kt * 64, al + i * 8 * 64);
      gload_lds16(bg + (size_t)i * 8 * K + kt * 64, bl + i * 8 * 64);
    }
    __syncthreads();

    bf16x8 af[4][2], bfr[4][2];
#pragma unroll
    for (int mi = 0; mi < 4; ++mi)
#pragma unroll
      for (int kk = 0; kk < 2; ++kk) {
        af[mi][kk]  = *(const bf16x8*)&As[(wm * 64 + mi * 16 + cl) * 64 + kk * 32 + g16 * 8];
        bfr[mi][kk] = *(const bf16x8*)&Bs[(wn * 64 + mi * 16 + cl) * 64 + kk * 32 + g16 * 8];
      }
#pragma unroll
    for (int mi = 0; mi < 4; ++mi)
#pragma unroll
      for (int ni = 0; ni < 4; ++ni)
#pragma unroll
        for (int kk = 0; kk < 2; ++kk)
          acc[mi][ni] = MFMA16(af[mi][kk], bfr[ni][kk], acc[mi][ni]);
    __syncthreads();
  }

#pragma unroll
  for (int mi = 0; mi < 4; ++mi) {
#pragma unroll
    for (int rr = 0; rr < 4; ++rr) {
      int r = tm * 128 + wm * 64 + mi * 16 + g16 * 4 + rr;
      if (MODE == 0) {
        int rp = permrow(r);
#pragma unroll
        for (int ni = 0; ni < 4; ++ni) {
          int c = (tn << 7) + wn * 64 + ni * 16 + cl;
          float v = acc[mi][ni][rr];
          if (c < 2048)      Cq[(size_t)rp * 2048 + c] = (bf16_t)(v * QSC);
          else if (c < 2560) Ck[(size_t)rp * 512 + (c - 2048)] = (bf16_t)v;
          else               Cv[(size_t)rp * 512 + (c - 2560)] = (bf16_t)v;
        }
      } else {
#pragma unroll
        for (int ni = 0; ni < 4; ++ni) {
          int c = (tn << 7) + wn * 64 + ni * 16 + cl;
          Cf[(size_t)r * 2048 + c] = acc[mi][ni][rr];
        }
      }
    }
  }
}

// m214-style swapped-QK^T flash attention. Grid: qc(8) x h(32) x n(8).
// 4 waves x 32 q-rows. Each lane owns q = lane&31 (softmax lane-local).
// S^T = mfma_32x32x16(K, Q): D col = lane&31 = q, row = crow(reg,hi) = kv.
// P stays in registers (cvt_pk + half-swap -> PV A-frags). V staged subtiled
// [kb][db][j][cc] and read via ds_read_b64_tr_b16 (corrected per-lane addr:
// chunk_base + (l&15)*8B). K/Q staged with pre-swizzled global src (T2/m173)
// and XOR'd b128 reads. KVBLK=64, double-buffered, 1 barrier/iter.
__global__ __launch_bounds__(256, 2) void k_attn(
    const bf16_t* __restrict__ Qp, const bf16_t* __restrict__ Kp,
    const bf16_t* __restrict__ Vp, bf16_t* __restrict__ O) {
  int bid = blockIdx.x;
  int qc = bid & 7;
  int h  = (bid >> 3) & 31;
  int n  = bid >> 8;
  int kvh = h >> 2;

  // 2 x 16KB: K[64 kv][64 d] (xor-swz rows) at 0, V subtiled
  // [kb 16][db 4][j 4][cc 16] at bf16 offset 4096.
  __shared__ bf16_t buf[2][8192];

  int tid = threadIdx.x, lane = tid & 63, w = tid >> 6;
  int l31 = lane & 31, hi = lane >> 5;
  int qrow_blk = n * 1024 + qc * 128;
  bf16_t* base = &buf[0][0];

  // ---- stage Q [128 q][64 d] (xor-swizzled rows) into buf[0] ----
#pragma unroll
  for (int r = 0; r < 4; ++r) {
    int ql = r * 32 + (tid >> 3);
    int cs = (tid & 7) << 4;                 // physical byte col slot
    int lc = (cs ^ ((ql & 7) << 4)) >> 1;    // logical bf16 col (pre-swizzle src)
    gload_lds16(Qp + (size_t)(qrow_blk + ql) * 2048 + h * 64 + lc,
                base + r * 2048 + w * 512);
  }
  __syncthreads();
  bf16x8 qf[4];
  {
    int q = w * 32 + l31;
    const bf16_t* qrow = base + q * 64;
    int sw = (q & 7) << 4;
#pragma unroll
    for (int c = 0; c < 4; ++c)
      qf[c] = *(const bf16x8*)(qrow + (((c * 32 + hi * 16) ^ sw) >> 1));
  }
  __syncthreads();   // Q reads done before KV staging overwrites

  f32x16 oacc0 = (f32x16)(0.0f), oacc1 = (f32x16)(0.0f);
  float m_run = -1e30f, l_run = 0.0f;

  auto stageKV = [&](int t) {
    bf16_t* bp = &buf[t & 1][0];
    int kvb = n * 1024 + t * 64;
#pragma unroll
    for (int r = 0; r < 2; ++r) {            // K: 2 x 4KB rounds
      int kv = r * 32 + (tid >> 3);
      int cs = (tid & 7) << 4;
      int lc = (cs ^ ((kv & 7) << 4)) >> 1;
      gload_lds16(Kp + (size_t)(kvb + kv) * 512 + kvh * 64 + lc,
                  bp + r * 2048 + w * 512);
    }
#pragma unroll
    for (int r = 0; r < 2; ++r) {            // V: subtiled, 2 x 4KB rounds
      int slot = r * 256 + tid;              // 16B slot index
      int sub = slot >> 3;                   // subtile = kb*4 + db
      int kb = sub >> 2, db = sub & 3;
      int j = (slot >> 1) & 3, hf = slot & 1;
      gload_lds16(Vp + (size_t)(kvb + kb * 4 + j) * 512 + kvh * 64 + db * 16 + hf * 8,
                  bp + 4096 + r * 2048 + w * 512);
    }
  };

  stageKV(0);
  for (int t = 0; t < 16; ++t) {
    __syncthreads();                 // drains stage(t); buffer handoff
    if (t < 15) stageKV(t + 1);      // overlaps with compute(t)
    const bf16_t* bp = &buf[t & 1][0];
    const bf16_t* Vs = bp + 4096;

#pragma unroll
    for (int s = 0; s < 2; ++s) {    // two 32-kv subtiles
      // ---- QK^T: st[r] = S[q=l31][kv = s*32 + crow(r,hi)] ----
      f32x16 st = (f32x16)(0.0f);
      {
        int kv = s * 32 + l31;
        const bf16_t* krow = bp + kv * 64;
        int sw = (kv & 7) << 4;
#pragma unroll
        for (int c = 0; c < 4; ++c) {
          bf16x8 kf = *(const bf16x8*)(krow + (((c * 32 + hi * 16) ^ sw) >> 1));
          st = MFMA32(kf, qf[c], st);
        }
      }
      // ---- softmax (lane-local, exp2 domain) ----
      float a0 = fmaxf(st[0], st[1]),   a1 = fmaxf(st[2], st[3]);
      float a2 = fmaxf(st[4], st[5]),   a3 = fmaxf(st[6], st[7]);
      float a4 = fmaxf(st[8], st[9]),   a5 = fmaxf(st[10], st[11]);
      float a6 = fmaxf(st[12], st[13]), a7 = fmaxf(st[14], st[15]);
      float pmax = fmaxf(fmaxf(fmaxf(a0, a1), fmaxf(a2, a3)),
                         fmaxf(fmaxf(a4, a5), fmaxf(a6, a7)));
      pmax = fmaxf(pmax, __shfl_xor(pmax, 32));
      if (!__all(pmax <= m_run + 11.0f)) {   // defer-max (T13)
        float mnew = fmaxf(m_run, pmax);
        float resc = exp2f(m_run - mnew);
        l_run *= resc;
#pragma unroll
        for (int e = 0; e < 16; ++e) { oacc0[e] *= resc; oacc1[e] *= resc; }
        m_run = mnew;
      }
      float rs = 0.0f;
      unsigned pw[8];
#pragma unroll
      for (int u = 0; u < 8; ++u) {
        float p0 = exp2f(st[2 * u] - m_run);
        float p1 = exp2f(st[2 * u + 1] - m_run);
        rs += p0 + p1;
        pw[u] = cvt_pk_bf16(p0, p1);   // lo=kv(2u), hi=kv(2u+1) of lane's set
      }
      rs += __shfl_xor(rs, 32);
      l_run += rs;

      // ---- PV: redistribute P halves in-register, V via tr_read ----
#pragma unroll
      for (int c = 0; c < 2; ++c) {
        unsigned w2, w0, w3, w1;
        swap32(pw[c * 4 + 2], pw[c * 4 + 0], hi, w2, w0);
        swap32(pw[c * 4 + 3], pw[c * 4 + 1], hi, w3, w1);
        union { unsigned u[4]; bf16x8 v; } pa;
        pa.u[0] = w0; pa.u[1] = w1; pa.u[2] = w2; pa.u[3] = w3;
        // pa elem e = P[q=l31][kv = s*32 + c*16 + hi*8 + e]
        int kb0 = s * 8 + c * 4 + hi * 2;
        int dbl = l31 >> 4;
        int cc8 = (l31 & 15) * 4;   // (l&15)*8 BYTES: lane's own 8B chunk slot
        const bf16_t* p00 = Vs + (kb0 * 4 + dbl) * 64 + cc8;
        const bf16_t* p01 = Vs + ((kb0 + 1) * 4 + dbl) * 64 + cc8;
        const bf16_t* p10 = Vs + (kb0 * 4 + 2 + dbl) * 64 + cc8;
        const bf16_t* p11 = Vs + ((kb0 + 1) * 4 + 2 + dbl) * 64 + cc8;
        s16x4 t00 = tr_b16(p00), t01 = tr_b16(p01);
        s16x4 t10 = tr_b16(p10), t11 = tr_b16(p11);
        asm volatile("s_waitcnt lgkmcnt(0)" ::: "memory");
        __builtin_amdgcn_sched_barrier(0);   // rule #18: fence MFMA hoisting
        union { s16x4 s4[2]; bf16x8 v; } vf0, vf1;
        vf0.s4[0] = t00; vf0.s4[1] = t01;
        vf1.s4[0] = t10; vf1.s4[1] = t11;
        oacc0 = MFMA32(pa.v, vf0.v, oacc0);
        oacc1 = MFMA32(pa.v, vf1.v, oacc1);
      }
    }
  }

  // ---- epilogue: normalize and write O ----
  float linv = 1.0f / l_run;
#pragma unroll
  for (int r = 0; r < 16; ++r) {
    int qrw = (r & 3) + 8 * (r >> 2) + 4 * hi;  // crow(r, hi)
    float li = __shfl(linv, qrw);
    size_t orow = (size_t)(qrow_blk + w * 32 + qrw) * 2048 + h * 64 + l31;
    O[orow]      = (bf16_t)(oacc0[r] * li);
    O[orow + 32] = (bf16_t)(oacc1[r] * li);
  }
}

extern "C" void kernel_launch(void* const* d_in, const int* in_sizes, int n_in,
                              void* d_out, int out_size, void* d_ws, size_t ws_size,
                              hipStream_t stream) {
  const float* X  = (const float*)d_in[0];
  const float* Wq = (const float*)d_in[1];
  const float* Wk = (const float*)d_in[2];
  const float* Wv = (const float*)d_in[3];
  const float* Wo = (const float*)d_in[4];
  float* out = (float*)d_out;

  char* ws = (char*)d_ws;
  const size_t MB = 1024 * 1024;
  bf16_t* Xb  = (bf16_t*)(ws + 0);
  bf16_t* WqT = (bf16_t*)(ws + 32 * MB);
  bf16_t* WkT = (bf16_t*)(ws + 40 * MB);
  bf16_t* WvT = (bf16_t*)(ws + 42 * MB);
  bf16_t* WoT = (bf16_t*)(ws + 44 * MB);
  bf16_t* Qp  = (bf16_t*)(ws + 52 * MB);
  bf16_t* Kp  = (bf16_t*)(ws + 84 * MB);
  bf16_t* Vp  = (bf16_t*)(ws + 92 * MB);
  bf16_t* Ob  = (bf16_t*)(ws + 100 * MB);

  k_convert<<<16384, 256, 0, stream>>>(X, Xb, 4194304);
  k_transpose<<<dim3(32, 32), 256, 0, stream>>>(Wq, WqT, 2048, 2048);
  k_transpose<<<dim3(8, 32), 256, 0, stream>>>(Wk, WkT, 2048, 512);
  k_transpose<<<dim3(8, 32), 256, 0, stream>>>(Wv, WvT, 2048, 512);
  k_transpose<<<dim3(32, 32), 256, 0, stream>>>(Wo, WoT, 2048, 2048);

  k_gemm<0><<<1536, 256, 0, stream>>>(Xb, WqT, WkT, WvT, Qp, Kp, Vp, nullptr);
  k_attn<<<2048, 256, 0, stream>>>(Qp, Kp, Vp, Ob);
  k_gemm<1><<<1024, 256, 0, stream>>>(Ob, WoT, nullptr, nullptr, nullptr, nullptr,
                                      nullptr, out);
}

// Round 6
// 354.680 us; speedup vs baseline: 1.9475x; 1.0357x over previous
//
#include <hip/hip_runtime.h>

typedef __bf16 bf16_t;
typedef __bf16 bf16x8 __attribute__((ext_vector_type(8)));
typedef __bf16 bf16x4 __attribute__((ext_vector_type(4)));
typedef float f32x4 __attribute__((ext_vector_type(4)));
typedef float f32x16 __attribute__((ext_vector_type(16)));
typedef short s16x4 __attribute__((ext_vector_type(4)));

#define MFMA16(A_, B_, C_) __builtin_amdgcn_mfma_f32_16x16x32_bf16((A_), (B_), (C_), 0, 0, 0)
#define MFMA32(A_, B_, C_) __builtin_amdgcn_mfma_f32_32x32x16_bf16((A_), (B_), (C_), 0, 0, 0)

// softmax scale folded into Q at GEMM0: 0.125 * log2(e) so p = exp2(s - m)
#define QSC 0.18033688011112042f

__device__ __forceinline__ void gload_lds16(const bf16_t* g, bf16_t* l) {
  __builtin_amdgcn_global_load_lds(
      (const __attribute__((address_space(1))) void*)g,
      (__attribute__((address_space(3))) void*)l, 16, 0, 0);
}

__device__ __forceinline__ unsigned cvt_pk_bf16(float a, float b) {
  unsigned r;
  asm("v_cvt_pk_bf16_f32 %0, %1, %2" : "=v"(r) : "v"(a), "v"(b));
  return r;
}

// HW transpose read. Within each 16-lane group, lane l supplies
// addr = chunk_base + (l&15)*8 BYTES; lane l receives column (l&15):
// elem j = chunk[j][l&15] of the 4x16-bf16 row-major 128B tile.
__device__ __forceinline__ s16x4 tr_b16(const bf16_t* p) {
  s16x4 d;
  unsigned off = (unsigned)(size_t)(const __attribute__((address_space(3))) bf16_t*)p;
  asm volatile("ds_read_b64_tr_b16 %0, %1" : "=v"(d) : "v"(off));
  return d;
}

// exchange: ra[l<32]=b[l+32], ra[l>=32]=a ; rb[l<32]=b, rb[l>=32]=a[l-32]
__device__ __forceinline__ void swap32(unsigned a, unsigned b, int hi,
                                       unsigned& ra, unsigned& rb) {
  unsigned bx = (unsigned)__shfl_xor((int)b, 32);
  unsigned ax = (unsigned)__shfl_xor((int)a, 32);
  ra = hi ? a : bx;
  rb = hi ? ax : b;
}

// fp32 -> bf16, 4 elements/thread
__global__ __launch_bounds__(256) void k_convert(const float* __restrict__ in,
                                                 bf16_t* __restrict__ out, int n4) {
  int i = blockIdx.x * 256 + threadIdx.x;
  if (i >= n4) return;
  float4 v = ((const float4*)in)[i];
  bf16x4 o;
  o[0] = (__bf16)v.x; o[1] = (__bf16)v.y; o[2] = (__bf16)v.z; o[3] = (__bf16)v.w;
  *(bf16x4*)(out + (size_t)i * 4) = o;
}

// out[c][r] = (bf16) in[r][c];  in is [R][C] fp32. 64x64 tiles, 256 threads.
__global__ __launch_bounds__(256) void k_transpose(const float* __restrict__ in,
                                                   bf16_t* __restrict__ out, int R, int C) {
  __shared__ float tile[64][65];
  int tx = threadIdx.x & 63;
  int ty = threadIdx.x >> 6;
  int bc = blockIdx.x * 64;
  int br = blockIdx.y * 64;
#pragma unroll
  for (int i = ty; i < 64; i += 4)
    tile[i][tx] = in[(size_t)(br + i) * C + bc + tx];
  __syncthreads();
#pragma unroll
  for (int i = ty; i < 64; i += 4)
    out[(size_t)(bc + i) * R + br + tx] = (bf16_t)tile[tx][i];
}

// block-split row permutation: original token row -> attention-layout row
__device__ __forceinline__ int permrow(int r) {
  int b  = r >> 12;
  int l  = r & 4095;
  int ix = (l >> 11) & 1;
  int sx = (l >> 6) & 31;
  int iy = (l >> 5) & 1;
  int sy = l & 31;
  return (b << 12) + (ix << 11) + (iy << 10) + (sx << 5) + sy;
}

// ---------------------------------------------------------------------------
// 256x256-tile 8-phase GEMM (HK-style schedule in plain HIP).
// C[M][N] = A[M][K] * B^T[N][K], K=2048, BK=64, 8 waves (2M x 4N), per-wave
// C = 128x64 = frag[8][4]. LDS = 2 dbuf x {A,B} x 2 halves x (128x64 bf16)
// = 128 KB (dynamic). Per phase: {ds_read quadrant frags || issue 1 half-tile
// prefetch (2 gload_lds)} -> s_barrier -> lgkmcnt(0) -> setprio(1) -> 16 MFMA
// -> setprio(0) -> s_barrier. Counted vmcnt(4) ONLY at phases 3 and 7.
// Dead-slot schedule (verified): B-slots are read only in phase 0/4, so B
// prefetches issue at phases 2,3 (buf0) and 6,7 (buf1); A-slots are read in
// all 4 phases of their K-tile, so A prefetches issue at phases 4,5 (buf0)
// and 0,1 (buf1, same-iteration tile t1 = just-in-time, 4 phases ahead).
// T2 XOR swizzle (slot ^= row&7) on both staging source and ds_read.
// MODE 0: fused QKV (N = 2048|512|512), bf16 out, permuted rows, Q scaled.
// MODE 1: fp32 out, straight rows (N = 2048).
// ---------------------------------------------------------------------------
#define LSLOT(B_, M_, H_) (lds + (((B_)*4 + (M_)*2 + (H_)) << 13))

#define STAGE_A(BUF, HF, T)                                                     \
  gload_lds16(aB + (size_t)((HF)*128) * 2048 + (T)*64, LSLOT(BUF, 0, HF) + wofs); \
  gload_lds16(aB + (size_t)((HF)*128 + 64) * 2048 + (T)*64,                     \
              LSLOT(BUF, 0, HF) + wofs + 4096);

#define STAGE_B(BUF, HF, T)                                                     \
  gload_lds16(bB + (size_t)((HF)*128) * 2048 + (T)*64, LSLOT(BUF, 1, HF) + wofs); \
  gload_lds16(bB + (size_t)((HF)*128 + 64) * 2048 + (T)*64,                     \
              LSLOT(BUF, 1, HF) + wofs + 4096);

#define LOAD_A(BUF, Q)                                                          \
  { const bf16_t* Ah = LSLOT(BUF, 0, wm);                                       \
    int r0 = ((Q)*32 + cl) * 64;                                                \
    af[0][0] = *(const bf16x8*)&Ah[r0 + ((g16 * 8) ^ swz8)];                    \
    af[0][1] = *(const bf16x8*)&Ah[r0 + ((32 + g16 * 8) ^ swz8)];               \
    af[1][0] = *(const bf16x8*)&Ah[r0 + 1024 + ((g16 * 8) ^ swz8)];             \
    af[1][1] = *(const bf16x8*)&Ah[r0 + 1024 + ((32 + g16 * 8) ^ swz8)]; }

#define LOAD_B(BUF)                                                             \
  { const bf16_t* Bh = LSLOT(BUF, 1, wn >> 1);                                  \
    _Pragma("unroll") for (int ni = 0; ni < 4; ++ni) {                          \
      int br = ((wn & 1) * 64 + ni * 16 + cl) * 64;                             \
      bfr[ni][0] = *(const bf16x8*)&Bh[br + ((g16 * 8) ^ swz8)];                \
      bfr[ni][1] = *(const bf16x8*)&Bh[br + ((32 + g16 * 8) ^ swz8)]; } }

#define MFMA_QUAD(Q)                                                            \
  _Pragma("unroll") for (int kk = 0; kk < 2; ++kk)                              \
    _Pragma("unroll") for (int ni = 0; ni < 4; ++ni) {                          \
      acc[2*(Q)][ni]   = MFMA16(af[0][kk], bfr[ni][kk], acc[2*(Q)][ni]);        \
      acc[2*(Q)+1][ni] = MFMA16(af[1][kk], bfr[ni][kk], acc[2*(Q)+1][ni]); }

#define PH_MID(VM4)                                                             \
  if (VM4) asm volatile("s_waitcnt vmcnt(4)" ::: "memory");                     \
  __builtin_amdgcn_s_barrier();                                                 \
  asm volatile("s_waitcnt lgkmcnt(0)" ::: "memory");                            \
  __builtin_amdgcn_s_setprio(1);

#define PH_END                                                                  \
  __builtin_amdgcn_s_setprio(0);                                                \
  __builtin_amdgcn_s_barrier();

template <int MODE>
__global__ __launch_bounds__(512, 2) void k_gemm8(
    const bf16_t* __restrict__ A,
    const bf16_t* __restrict__ B0, const bf16_t* __restrict__ B1,
    const bf16_t* __restrict__ B2,
    bf16_t* __restrict__ Cq, bf16_t* __restrict__ Ck, bf16_t* __restrict__ Cv,
    float* __restrict__ Cf) {
  extern __shared__ bf16_t lds[];

  // XCD-aware bijective swizzle (nwg divisible by 8 in both modes)
  int nwg = gridDim.x;
  int cpx = nwg >> 3;
  int bid = blockIdx.x;
  int swz = (bid & 7) * cpx + (bid >> 3);
  int tm = swz & 31;        // 32 M-tiles (M=8192)
  int tn = swz >> 5;        // 12 (MODE0) or 8 (MODE1) N-tiles

  const bf16_t* Bp;
  int brow;
  if (MODE == 0) {
    if (tn < 8)       { Bp = B0; brow = tn << 8; }
    else if (tn < 10) { Bp = B1; brow = (tn - 8) << 8; }
    else              { Bp = B2; brow = (tn - 10) << 8; }
  } else {
    Bp = B0; brow = tn << 8;
  }

  int tid = threadIdx.x;
  int lane = tid & 63;
  int w = tid >> 6;                  // 0..7
  int wm = w >> 2, wn = w & 3;       // 2 x 4 wave grid
  int g16 = lane >> 4, cl = lane & 15;
  int swz8 = (cl & 7) << 3;
  int wofs = w << 9;                 // w*512 elements (staging dest base)

  // staging source: row = srow (+64 per r, +128 per half), pre-swizzled col
  int srow = tid >> 3;                                  // 0..63
  int lc = (((tid & 7) ^ (srow & 7)) << 3);             // logical col for slot
  const bf16_t* aB = A + (size_t)(tm * 256 + srow) * 2048 + lc;
  const bf16_t* bB = Bp + (size_t)(brow + srow) * 2048 + lc;

  f32x4 acc[8][4];
#pragma unroll
  for (int i = 0; i < 8; ++i)
#pragma unroll
    for (int j = 0; j < 4; ++j) acc[i][j] = (f32x4)(0.0f);

  // ---- prologue: tile0 (A+B, buf0) + tile1 B (buf1); drain tile0 ----
  STAGE_A(0, 0, 0); STAGE_A(0, 1, 0);
  STAGE_B(0, 0, 0); STAGE_B(0, 1, 0);
  STAGE_B(1, 0, 1); STAGE_B(1, 1, 1);
  asm volatile("s_waitcnt vmcnt(4)" ::: "memory");
  __builtin_amdgcn_s_barrier();

  for (int it2 = 0; it2 < 16; ++it2) {
    int t1 = 2 * it2 + 1;
    int tf = 2 * it2 + 2; if (tf > 31) tf = 31;  // clamped: redundant, unread
    int tg = 2 * it2 + 3; if (tg > 31) tg = 31;
    bf16x8 af[2][2], bfr[4][2];
    // phase 0: quadrant 0 of even tile (buf0); stage buf1.A half0 (t1)
    LOAD_B(0); LOAD_A(0, 0);
    STAGE_A(1, 0, t1);
    PH_MID(0); MFMA_QUAD(0); PH_END;
    // phase 1
    LOAD_A(0, 1);
    STAGE_A(1, 1, t1);
    PH_MID(0); MFMA_QUAD(1); PH_END;
    // phase 2 (buf0.B slots dead since end of phase 0)
    LOAD_A(0, 2);
    STAGE_B(0, 0, tf);
    PH_MID(0); MFMA_QUAD(2); PH_END;
    // phase 3: vmcnt(4) drains through phase 1 -> tile t1 (buf1) complete
    LOAD_A(0, 3);
    STAGE_B(0, 1, tf);
    PH_MID(1); MFMA_QUAD(3); PH_END;
    // phase 4: quadrant 0 of odd tile (buf1); buf0.A slots dead after ph3
    LOAD_B(1); LOAD_A(1, 0);
    STAGE_A(0, 0, tf);
    PH_MID(0); MFMA_QUAD(0); PH_END;
    // phase 5
    LOAD_A(1, 1);
    STAGE_A(0, 1, tf);
    PH_MID(0); MFMA_QUAD(1); PH_END;
    // phase 6 (buf1.B slots dead since end of phase 4)
    LOAD_A(1, 2);
    STAGE_B(1, 0, tg);
    PH_MID(0); MFMA_QUAD(2); PH_END;
    // phase 7: vmcnt(4) drains through phase 5 -> tile tf (buf0) complete
    LOAD_A(1, 3);
    STAGE_B(1, 1, tg);
    PH_MID(1); MFMA_QUAD(3); PH_END;
  }

  // ---- epilogue ----
#pragma unroll
  for (int mi = 0; mi < 8; ++mi) {
#pragma unroll
    for (int rr = 0; rr < 4; ++rr) {
      int r = tm * 256 + wm * 128 + mi * 16 + g16 * 4 + rr;
      if (MODE == 0) {
        int rp = permrow(r);
#pragma unroll
        for (int ni = 0; ni < 4; ++ni) {
          int c = tn * 256 + wn * 64 + ni * 16 + cl;
          float v = acc[mi][ni][rr];
          if (c < 2048)      Cq[(size_t)rp * 2048 + c] = (bf16_t)(v * QSC);
          else if (c < 2560) Ck[(size_t)rp * 512 + (c - 2048)] = (bf16_t)v;
          else               Cv[(size_t)rp * 512 + (c - 2560)] = (bf16_t)v;
        }
      } else {
#pragma unroll
        for (int ni = 0; ni < 4; ++ni) {
          int c = tn * 256 + wn * 64 + ni * 16 + cl;
          Cf[(size_t)r * 2048 + c] = acc[mi][ni][rr];
        }
      }
    }
  }
}

// m214-style swapped-QK^T flash attention (unchanged from round 5).
__global__ __launch_bounds__(256, 2) void k_attn(
    const bf16_t* __restrict__ Qp, const bf16_t* __restrict__ Kp,
    const bf16_t* __restrict__ Vp, bf16_t* __restrict__ O) {
  int bid = blockIdx.x;
  int qc = bid & 7;
  int h  = (bid >> 3) & 31;
  int n  = bid >> 8;
  int kvh = h >> 2;

  __shared__ bf16_t buf[2][8192];

  int tid = threadIdx.x, lane = tid & 63, w = tid >> 6;
  int l31 = lane & 31, hi = lane >> 5;
  int qrow_blk = n * 1024 + qc * 128;
  bf16_t* base = &buf[0][0];

#pragma unroll
  for (int r = 0; r < 4; ++r) {
    int ql = r * 32 + (tid >> 3);
    int cs = (tid & 7) << 4;
    int lc = (cs ^ ((ql & 7) << 4)) >> 1;
    gload_lds16(Qp + (size_t)(qrow_blk + ql) * 2048 + h * 64 + lc,
                base + r * 2048 + w * 512);
  }
  __syncthreads();
  bf16x8 qf[4];
  {
    int q = w * 32 + l31;
    const bf16_t* qrow = base + q * 64;
    int sw = (q & 7) << 4;
#pragma unroll
    for (int c = 0; c < 4; ++c)
      qf[c] = *(const bf16x8*)(qrow + (((c * 32 + hi * 16) ^ sw) >> 1));
  }
  __syncthreads();

  f32x16 oacc0 = (f32x16)(0.0f), oacc1 = (f32x16)(0.0f);
  float m_run = -1e30f, l_run = 0.0f;

  auto stageKV = [&](int t) {
    bf16_t* bp = &buf[t & 1][0];
    int kvb = n * 1024 + t * 64;
#pragma unroll
    for (int r = 0; r < 2; ++r) {
      int kv = r * 32 + (tid >> 3);
      int cs = (tid & 7) << 4;
      int lc = (cs ^ ((kv & 7) << 4)) >> 1;
      gload_lds16(Kp + (size_t)(kvb + kv) * 512 + kvh * 64 + lc,
                  bp + r * 2048 + w * 512);
    }
#pragma unroll
    for (int r = 0; r < 2; ++r) {
      int slot = r * 256 + tid;
      int sub = slot >> 3;
      int kb = sub >> 2, db = sub & 3;
      int j = (slot >> 1) & 3, hf = slot & 1;
      gload_lds16(Vp + (size_t)(kvb + kb * 4 + j) * 512 + kvh * 64 + db * 16 + hf * 8,
                  bp + 4096 + r * 2048 + w * 512);
    }
  };

  stageKV(0);
  for (int t = 0; t < 16; ++t) {
    __syncthreads();
    if (t < 15) stageKV(t + 1);
    const bf16_t* bp = &buf[t & 1][0];
    const bf16_t* Vs = bp + 4096;

#pragma unroll
    for (int s = 0; s < 2; ++s) {
      f32x16 st = (f32x16)(0.0f);
      {
        int kv = s * 32 + l31;
        const bf16_t* krow = bp + kv * 64;
        int sw = (kv & 7) << 4;
#pragma unroll
        for (int c = 0; c < 4; ++c) {
          bf16x8 kf = *(const bf16x8*)(krow + (((c * 32 + hi * 16) ^ sw) >> 1));
          st = MFMA32(kf, qf[c], st);
        }
      }
      float a0 = fmaxf(st[0], st[1]),   a1 = fmaxf(st[2], st[3]);
      float a2 = fmaxf(st[4], st[5]),   a3 = fmaxf(st[6], st[7]);
      float a4 = fmaxf(st[8], st[9]),   a5 = fmaxf(st[10], st[11]);
      float a6 = fmaxf(st[12], st[13]), a7 = fmaxf(st[14], st[15]);
      float pmax = fmaxf(fmaxf(fmaxf(a0, a1), fmaxf(a2, a3)),
                         fmaxf(fmaxf(a4, a5), fmaxf(a6, a7)));
      pmax = fmaxf(pmax, __shfl_xor(pmax, 32));
      if (!__all(pmax <= m_run + 11.0f)) {
        float mnew = fmaxf(m_run, pmax);
        float resc = exp2f(m_run - mnew);
        l_run *= resc;
#pragma unroll
        for (int e = 0; e < 16; ++e) { oacc0[e] *= resc; oacc1[e] *= resc; }
        m_run = mnew;
      }
      float rs = 0.0f;
      unsigned pw[8];
#pragma unroll
      for (int u = 0; u < 8; ++u) {
        float p0 = exp2f(st[2 * u] - m_run);
        float p1 = exp2f(st[2 * u + 1] - m_run);
        rs += p0 + p1;
        pw[u] = cvt_pk_bf16(p0, p1);
      }
      rs += __shfl_xor(rs, 32);
      l_run += rs;

#pragma unroll
      for (int c = 0; c < 2; ++c) {
        unsigned w2, w0, w3, w1;
        swap32(pw[c * 4 + 2], pw[c * 4 + 0], hi, w2, w0);
        swap32(pw[c * 4 + 3], pw[c * 4 + 1], hi, w3, w1);
        union { unsigned u[4]; bf16x8 v; } pa;
        pa.u[0] = w0; pa.u[1] = w1; pa.u[2] = w2; pa.u[3] = w3;
        int kb0 = s * 8 + c * 4 + hi * 2;
        int dbl = l31 >> 4;
        int cc8 = (l31 & 15) * 4;
        const bf16_t* p00 = Vs + (kb0 * 4 + dbl) * 64 + cc8;
        const bf16_t* p01 = Vs + ((kb0 + 1) * 4 + dbl) * 64 + cc8;
        const bf16_t* p10 = Vs + (kb0 * 4 + 2 + dbl) * 64 + cc8;
        const bf16_t* p11 = Vs + ((kb0 + 1) * 4 + 2 + dbl) * 64 + cc8;
        s16x4 t00 = tr_b16(p00), t01 = tr_b16(p01);
        s16x4 t10 = tr_b16(p10), t11 = tr_b16(p11);
        asm volatile("s_waitcnt lgkmcnt(0)" ::: "memory");
        __builtin_amdgcn_sched_barrier(0);
        union { s16x4 s4[2]; bf16x8 v; } vf0, vf1;
        vf0.s4[0] = t00; vf0.s4[1] = t01;
        vf1.s4[0] = t10; vf1.s4[1] = t11;
        oacc0 = MFMA32(pa.v, vf0.v, oacc0);
        oacc1 = MFMA32(pa.v, vf1.v, oacc1);
      }
    }
  }

  float linv = 1.0f / l_run;
#pragma unroll
  for (int r = 0; r < 16; ++r) {
    int qrw = (r & 3) + 8 * (r >> 2) + 4 * hi;
    float li = __shfl(linv, qrw);
    size_t orow = (size_t)(qrow_blk + w * 32 + qrw) * 2048 + h * 64 + l31;
    O[orow]      = (bf16_t)(oacc0[r] * li);
    O[orow + 32] = (bf16_t)(oacc1[r] * li);
  }
}

extern "C" void kernel_launch(void* const* d_in, const int* in_sizes, int n_in,
                              void* d_out, int out_size, void* d_ws, size_t ws_size,
                              hipStream_t stream) {
  const float* X  = (const float*)d_in[0];
  const float* Wq = (const float*)d_in[1];
  const float* Wk = (const float*)d_in[2];
  const float* Wv = (const float*)d_in[3];
  const float* Wo = (const float*)d_in[4];
  float* out = (float*)d_out;

  char* ws = (char*)d_ws;
  const size_t MB = 1024 * 1024;
  bf16_t* Xb  = (bf16_t*)(ws + 0);
  bf16_t* WqT = (bf16_t*)(ws + 32 * MB);
  bf16_t* WkT = (bf16_t*)(ws + 40 * MB);
  bf16_t* WvT = (bf16_t*)(ws + 42 * MB);
  bf16_t* WoT = (bf16_t*)(ws + 44 * MB);
  bf16_t* Qp  = (bf16_t*)(ws + 52 * MB);
  bf16_t* Kp  = (bf16_t*)(ws + 84 * MB);
  bf16_t* Vp  = (bf16_t*)(ws + 92 * MB);
  bf16_t* Ob  = (bf16_t*)(ws + 100 * MB);

  // allow 128 KB dynamic LDS for the 8-phase GEMM (host-side, capture-safe)
  hipFuncSetAttribute(reinterpret_cast<const void*>(&k_gemm8<0>),
                      hipFuncAttributeMaxDynamicSharedMemorySize, 131072);
  hipFuncSetAttribute(reinterpret_cast<const void*>(&k_gemm8<1>),
                      hipFuncAttributeMaxDynamicSharedMemorySize, 131072);

  k_convert<<<16384, 256, 0, stream>>>(X, Xb, 4194304);
  k_transpose<<<dim3(32, 32), 256, 0, stream>>>(Wq, WqT, 2048, 2048);
  k_transpose<<<dim3(8, 32), 256, 0, stream>>>(Wk, WkT, 2048, 512);
  k_transpose<<<dim3(8, 32), 256, 0, stream>>>(Wv, WvT, 2048, 512);
  k_transpose<<<dim3(32, 32), 256, 0, stream>>>(Wo, WoT, 2048, 2048);

  k_gemm8<0><<<384, 512, 131072, stream>>>(Xb, WqT, WkT, WvT, Qp, Kp, Vp, nullptr);
  k_attn<<<2048, 256, 0, stream>>>(Qp, Kp, Vp, Ob);
  k_gemm8<1><<<256, 512, 131072, stream>>>(Ob, WoT, nullptr, nullptr, nullptr,
                                           nullptr, nullptr, out);
}

// Round 7
// 354.248 us; speedup vs baseline: 1.9498x; 1.0012x over previous
//
#include <hip/hip_runtime.h>

typedef __bf16 bf16_t;
typedef __bf16 bf16x8 __attribute__((ext_vector_type(8)));
typedef __bf16 bf16x4 __attribute__((ext_vector_type(4)));
typedef float f32x4 __attribute__((ext_vector_type(4)));
typedef float f32x16 __attribute__((ext_vector_type(16)));
typedef short s16x4 __attribute__((ext_vector_type(4)));
typedef short s16x8 __attribute__((ext_vector_type(8)));

#define MFMA16(A_, B_, C_) __builtin_amdgcn_mfma_f32_16x16x32_bf16((A_), (B_), (C_), 0, 0, 0)
#define MFMA32(A_, B_, C_) __builtin_amdgcn_mfma_f32_32x32x16_bf16((A_), (B_), (C_), 0, 0, 0)

// softmax scale folded into Q at GEMM0: 0.125 * log2(e) so p = exp2(s - m)
#define QSC 0.18033688011112042f

__device__ __forceinline__ void gload_lds16(const bf16_t* g, bf16_t* l) {
  __builtin_amdgcn_global_load_lds(
      (const __attribute__((address_space(1))) void*)g,
      (__attribute__((address_space(3))) void*)l, 16, 0, 0);
}

__device__ __forceinline__ unsigned cvt_pk_bf16(float a, float b) {
  unsigned r;
  asm("v_cvt_pk_bf16_f32 %0, %1, %2" : "=v"(r) : "v"(a), "v"(b));
  return r;
}

// HW transpose read (attn). Lane l supplies chunk_base + (l&15)*8B and
// receives column (l&15): elem j = chunk[j][l&15] of a 4x16-bf16 tile.
__device__ __forceinline__ s16x4 tr_b16(const bf16_t* p) {
  s16x4 d;
  unsigned off = (unsigned)(size_t)(const __attribute__((address_space(3))) bf16_t*)p;
  asm volatile("ds_read_b64_tr_b16 %0, %1" : "=v"(d) : "v"(off));
  return d;
}

// b128 LDS read as volatile inline asm: INVISIBLE to the SIInsertWaitcnts
// pass, so the compiler cannot insert s_waitcnt vmcnt(0) before it to order
// it against outstanding global_load_lds (LDS-DMA) ops. With a dynamic
// extern __shared__ buffer + pointer arithmetic, alias analysis can't
// disambiguate slots, and the compiler's conservative vmcnt(0)-per-phase
// was draining the whole prefetch pipeline (round-6 evidence: 8-phase time
// == 2-phase time == m218's drain0 signature). Ordering now rests on the
// explicit counted vmcnt(4) + per-phase lgkmcnt(0) + sched_barrier(0).
union B128 { s16x8 s; bf16x8 b; };

#define DSR(PTR, U)                                                           \
  do {                                                                        \
    unsigned _o = (unsigned)(size_t)                                          \
        (const __attribute__((address_space(3))) bf16_t*)(PTR);               \
    asm volatile("ds_read_b128 %0, %1" : "=v"((U).s) : "v"(_o));              \
  } while (0)

// exchange: ra[l<32]=b[l+32], ra[l>=32]=a ; rb[l<32]=b, rb[l>=32]=a[l-32]
__device__ __forceinline__ void swap32(unsigned a, unsigned b, int hi,
                                       unsigned& ra, unsigned& rb) {
  unsigned bx = (unsigned)__shfl_xor((int)b, 32);
  unsigned ax = (unsigned)__shfl_xor((int)a, 32);
  ra = hi ? a : bx;
  rb = hi ? ax : b;
}

// fp32 -> bf16, 4 elements/thread
__global__ __launch_bounds__(256) void k_convert(const float* __restrict__ in,
                                                 bf16_t* __restrict__ out, int n4) {
  int i = blockIdx.x * 256 + threadIdx.x;
  if (i >= n4) return;
  float4 v = ((const float4*)in)[i];
  bf16x4 o;
  o[0] = (__bf16)v.x; o[1] = (__bf16)v.y; o[2] = (__bf16)v.z; o[3] = (__bf16)v.w;
  *(bf16x4*)(out + (size_t)i * 4) = o;
}

// out[c][r] = (bf16) in[r][c];  in is [R][C] fp32. 64x64 tiles, 256 threads.
__global__ __launch_bounds__(256) void k_transpose(const float* __restrict__ in,
                                                   bf16_t* __restrict__ out, int R, int C) {
  __shared__ float tile[64][65];
  int tx = threadIdx.x & 63;
  int ty = threadIdx.x >> 6;
  int bc = blockIdx.x * 64;
  int br = blockIdx.y * 64;
#pragma unroll
  for (int i = ty; i < 64; i += 4)
    tile[i][tx] = in[(size_t)(br + i) * C + bc + tx];
  __syncthreads();
#pragma unroll
  for (int i = ty; i < 64; i += 4)
    out[(size_t)(bc + i) * R + br + tx] = (bf16_t)tile[tx][i];
}

// block-split row permutation: original token row -> attention-layout row
__device__ __forceinline__ int permrow(int r) {
  int b  = r >> 12;
  int l  = r & 4095;
  int ix = (l >> 11) & 1;
  int sx = (l >> 6) & 31;
  int iy = (l >> 5) & 1;
  int sy = l & 31;
  return (b << 12) + (ix << 11) + (iy << 10) + (sx << 5) + sy;
}

// ---------------------------------------------------------------------------
// 256x256-tile 8-phase GEMM. Same schedule as round 6 (ledger re-verified:
// prologue 12 issued / vmcnt(4) drains tile0; steady state: ph3 vmcnt(4)
// completes buf1 tile, ph7 vmcnt(4) completes buf0 tile; B-slots die after
// ph0/4, A-slots after ph3/7). Only change: fragment ds_reads are inline-asm
// (see DSR above) so the counted-vmcnt pipeline actually survives codegen.
// ---------------------------------------------------------------------------
#define LSLOT(B_, M_, H_) (lds + (((B_)*4 + (M_)*2 + (H_)) << 13))

#define STAGE_A(BUF, HF, T)                                                     \
  gload_lds16(aB + (size_t)((HF)*128) * 2048 + (T)*64, LSLOT(BUF, 0, HF) + wofs); \
  gload_lds16(aB + (size_t)((HF)*128 + 64) * 2048 + (T)*64,                     \
              LSLOT(BUF, 0, HF) + wofs + 4096);

#define STAGE_B(BUF, HF, T)                                                     \
  gload_lds16(bB + (size_t)((HF)*128) * 2048 + (T)*64, LSLOT(BUF, 1, HF) + wofs); \
  gload_lds16(bB + (size_t)((HF)*128 + 64) * 2048 + (T)*64,                     \
              LSLOT(BUF, 1, HF) + wofs + 4096);

#define LOAD_A(BUF, Q)                                                          \
  { const bf16_t* Ah = LSLOT(BUF, 0, wm) + ((Q)*32 + cl) * 64;                  \
    DSR(Ah + ((g16 * 8) ^ swz8), af[0][0]);                                     \
    DSR(Ah + ((32 + g16 * 8) ^ swz8), af[0][1]);                                \
    DSR(Ah + 1024 + ((g16 * 8) ^ swz8), af[1][0]);                              \
    DSR(Ah + 1024 + ((32 + g16 * 8) ^ swz8), af[1][1]); }

#define LOAD_B(BUF)                                                             \
  { const bf16_t* Bh = LSLOT(BUF, 1, wn >> 1);                                  \
    _Pragma("unroll") for (int ni = 0; ni < 4; ++ni) {                          \
      const bf16_t* Br = Bh + ((wn & 1) * 64 + ni * 16 + cl) * 64;              \
      DSR(Br + ((g16 * 8) ^ swz8), bfr[ni][0]);                                 \
      DSR(Br + ((32 + g16 * 8) ^ swz8), bfr[ni][1]); } }

#define MFMA_QUAD(Q)                                                            \
  _Pragma("unroll") for (int kk = 0; kk < 2; ++kk)                              \
    _Pragma("unroll") for (int ni = 0; ni < 4; ++ni) {                          \
      acc[2*(Q)][ni]   = MFMA16(af[0][kk].b, bfr[ni][kk].b, acc[2*(Q)][ni]);    \
      acc[2*(Q)+1][ni] = MFMA16(af[1][kk].b, bfr[ni][kk].b, acc[2*(Q)+1][ni]); }

#define PH_MID(VM4)                                                             \
  if (VM4) asm volatile("s_waitcnt vmcnt(4)" ::: "memory");                     \
  __builtin_amdgcn_s_barrier();                                                 \
  asm volatile("s_waitcnt lgkmcnt(0)" ::: "memory");                            \
  __builtin_amdgcn_sched_barrier(0);                                            \
  __builtin_amdgcn_s_setprio(1);

#define PH_END                                                                  \
  __builtin_amdgcn_sched_barrier(0);                                            \
  __builtin_amdgcn_s_setprio(0);                                                \
  __builtin_amdgcn_s_barrier();

template <int MODE>
__global__ __launch_bounds__(512, 2) void k_gemm8(
    const bf16_t* __restrict__ A,
    const bf16_t* __restrict__ B0, const bf16_t* __restrict__ B1,
    const bf16_t* __restrict__ B2,
    bf16_t* __restrict__ Cq, bf16_t* __restrict__ Ck, bf16_t* __restrict__ Cv,
    float* __restrict__ Cf) {
  extern __shared__ bf16_t lds[];

  // XCD-aware bijective swizzle (nwg divisible by 8 in both modes)
  int nwg = gridDim.x;
  int cpx = nwg >> 3;
  int bid = blockIdx.x;
  int swz = (bid & 7) * cpx + (bid >> 3);
  int tm = swz & 31;        // 32 M-tiles (M=8192)
  int tn = swz >> 5;        // 12 (MODE0) or 8 (MODE1) N-tiles

  const bf16_t* Bp;
  int brow;
  if (MODE == 0) {
    if (tn < 8)       { Bp = B0; brow = tn << 8; }
    else if (tn < 10) { Bp = B1; brow = (tn - 8) << 8; }
    else              { Bp = B2; brow = (tn - 10) << 8; }
  } else {
    Bp = B0; brow = tn << 8;
  }

  int tid = threadIdx.x;
  int lane = tid & 63;
  int w = tid >> 6;                  // 0..7
  int wm = w >> 2, wn = w & 3;       // 2 x 4 wave grid
  int g16 = lane >> 4, cl = lane & 15;
  int swz8 = (cl & 7) << 3;
  int wofs = w << 9;                 // w*512 elements (staging dest base)

  // staging source: row = srow (+64 per r, +128 per half), pre-swizzled col
  int srow = tid >> 3;                                  // 0..63
  int lc = (((tid & 7) ^ (srow & 7)) << 3);             // logical col for slot
  const bf16_t* aB = A + (size_t)(tm * 256 + srow) * 2048 + lc;
  const bf16_t* bB = Bp + (size_t)(brow + srow) * 2048 + lc;

  f32x4 acc[8][4];
#pragma unroll
  for (int i = 0; i < 8; ++i)
#pragma unroll
    for (int j = 0; j < 4; ++j) acc[i][j] = (f32x4)(0.0f);

  // ---- prologue: tile0 (A+B, buf0) + tile1 B (buf1); drain tile0 ----
  STAGE_A(0, 0, 0); STAGE_A(0, 1, 0);
  STAGE_B(0, 0, 0); STAGE_B(0, 1, 0);
  STAGE_B(1, 0, 1); STAGE_B(1, 1, 1);
  asm volatile("s_waitcnt vmcnt(4)" ::: "memory");
  __builtin_amdgcn_s_barrier();

  for (int it2 = 0; it2 < 16; ++it2) {
    int t1 = 2 * it2 + 1;
    int tf = 2 * it2 + 2; if (tf > 31) tf = 31;  // clamped: redundant, unread
    int tg = 2 * it2 + 3; if (tg > 31) tg = 31;
    B128 af[2][2], bfr[4][2];
    // phase 0: quadrant 0 of even tile (buf0); stage buf1.A half0 (t1)
    STAGE_A(1, 0, t1);
    LOAD_B(0); LOAD_A(0, 0);
    PH_MID(0); MFMA_QUAD(0); PH_END;
    // phase 1
    STAGE_A(1, 1, t1);
    LOAD_A(0, 1);
    PH_MID(0); MFMA_QUAD(1); PH_END;
    // phase 2 (buf0.B slots dead since end of phase 0)
    STAGE_B(0, 0, tf);
    LOAD_A(0, 2);
    PH_MID(0); MFMA_QUAD(2); PH_END;
    // phase 3: vmcnt(4) drains through phase 1 -> tile t1 (buf1) complete
    STAGE_B(0, 1, tf);
    LOAD_A(0, 3);
    PH_MID(1); MFMA_QUAD(3); PH_END;
    // phase 4: quadrant 0 of odd tile (buf1); buf0.A slots dead after ph3
    STAGE_A(0, 0, tf);
    LOAD_B(1); LOAD_A(1, 0);
    PH_MID(0); MFMA_QUAD(0); PH_END;
    // phase 5
    STAGE_A(0, 1, tf);
    LOAD_A(1, 1);
    PH_MID(0); MFMA_QUAD(1); PH_END;
    // phase 6 (buf1.B slots dead since end of phase 4)
    STAGE_B(1, 0, tg);
    LOAD_A(1, 2);
    PH_MID(0); MFMA_QUAD(2); PH_END;
    // phase 7: vmcnt(4) drains through phase 5 -> tile tf (buf0) complete
    STAGE_B(1, 1, tg);
    LOAD_A(1, 3);
    PH_MID(1); MFMA_QUAD(3); PH_END;
  }

  // ---- epilogue ----
#pragma unroll
  for (int mi = 0; mi < 8; ++mi) {
#pragma unroll
    for (int rr = 0; rr < 4; ++rr) {
      int r = tm * 256 + wm * 128 + mi * 16 + g16 * 4 + rr;
      if (MODE == 0) {
        int rp = permrow(r);
#pragma unroll
        for (int ni = 0; ni < 4; ++ni) {
          int c = tn * 256 + wn * 64 + ni * 16 + cl;
          float v = acc[mi][ni][rr];
          if (c < 2048)      Cq[(size_t)rp * 2048 + c] = (bf16_t)(v * QSC);
          else if (c < 2560) Ck[(size_t)rp * 512 + (c - 2048)] = (bf16_t)v;
          else               Cv[(size_t)rp * 512 + (c - 2560)] = (bf16_t)v;
        }
      } else {
#pragma unroll
        for (int ni = 0; ni < 4; ++ni) {
          int c = tn * 256 + wn * 64 + ni * 16 + cl;
          Cf[(size_t)r * 2048 + c] = acc[mi][ni][rr];
        }
      }
    }
  }
}

// m214-style swapped-QK^T flash attention (unchanged from round 5).
__global__ __launch_bounds__(256, 2) void k_attn(
    const bf16_t* __restrict__ Qp, const bf16_t* __restrict__ Kp,
    const bf16_t* __restrict__ Vp, bf16_t* __restrict__ O) {
  int bid = blockIdx.x;
  int qc = bid & 7;
  int h  = (bid >> 3) & 31;
  int n  = bid >> 8;
  int kvh = h >> 2;

  __shared__ bf16_t buf[2][8192];

  int tid = threadIdx.x, lane = tid & 63, w = tid >> 6;
  int l31 = lane & 31, hi = lane >> 5;
  int qrow_blk = n * 1024 + qc * 128;
  bf16_t* base = &buf[0][0];

#pragma unroll
  for (int r = 0; r < 4; ++r) {
    int ql = r * 32 + (tid >> 3);
    int cs = (tid & 7) << 4;
    int lc = (cs ^ ((ql & 7) << 4)) >> 1;
    gload_lds16(Qp + (size_t)(qrow_blk + ql) * 2048 + h * 64 + lc,
                base + r * 2048 + w * 512);
  }
  __syncthreads();
  bf16x8 qf[4];
  {
    int q = w * 32 + l31;
    const bf16_t* qrow = base + q * 64;
    int sw = (q & 7) << 4;
#pragma unroll
    for (int c = 0; c < 4; ++c)
      qf[c] = *(const bf16x8*)(qrow + (((c * 32 + hi * 16) ^ sw) >> 1));
  }
  __syncthreads();

  f32x16 oacc0 = (f32x16)(0.0f), oacc1 = (f32x16)(0.0f);
  float m_run = -1e30f, l_run = 0.0f;

  auto stageKV = [&](int t) {
    bf16_t* bp = &buf[t & 1][0];
    int kvb = n * 1024 + t * 64;
#pragma unroll
    for (int r = 0; r < 2; ++r) {
      int kv = r * 32 + (tid >> 3);
      int cs = (tid & 7) << 4;
      int lc = (cs ^ ((kv & 7) << 4)) >> 1;
      gload_lds16(Kp + (size_t)(kvb + kv) * 512 + kvh * 64 + lc,
                  bp + r * 2048 + w * 512);
    }
#pragma unroll
    for (int r = 0; r < 2; ++r) {
      int slot = r * 256 + tid;
      int sub = slot >> 3;
      int kb = sub >> 2, db = sub & 3;
      int j = (slot >> 1) & 3, hf = slot & 1;
      gload_lds16(Vp + (size_t)(kvb + kb * 4 + j) * 512 + kvh * 64 + db * 16 + hf * 8,
                  bp + 4096 + r * 2048 + w * 512);
    }
  };

  stageKV(0);
  for (int t = 0; t < 16; ++t) {
    __syncthreads();
    if (t < 15) stageKV(t + 1);
    const bf16_t* bp = &buf[t & 1][0];
    const bf16_t* Vs = bp + 4096;

#pragma unroll
    for (int s = 0; s < 2; ++s) {
      f32x16 st = (f32x16)(0.0f);
      {
        int kv = s * 32 + l31;
        const bf16_t* krow = bp + kv * 64;
        int sw = (kv & 7) << 4;
#pragma unroll
        for (int c = 0; c < 4; ++c) {
          bf16x8 kf = *(const bf16x8*)(krow + (((c * 32 + hi * 16) ^ sw) >> 1));
          st = MFMA32(kf, qf[c], st);
        }
      }
      float a0 = fmaxf(st[0], st[1]),   a1 = fmaxf(st[2], st[3]);
      float a2 = fmaxf(st[4], st[5]),   a3 = fmaxf(st[6], st[7]);
      float a4 = fmaxf(st[8], st[9]),   a5 = fmaxf(st[10], st[11]);
      float a6 = fmaxf(st[12], st[13]), a7 = fmaxf(st[14], st[15]);
      float pmax = fmaxf(fmaxf(fmaxf(a0, a1), fmaxf(a2, a3)),
                         fmaxf(fmaxf(a4, a5), fmaxf(a6, a7)));
      pmax = fmaxf(pmax, __shfl_xor(pmax, 32));
      if (!__all(pmax <= m_run + 11.0f)) {
        float mnew = fmaxf(m_run, pmax);
        float resc = exp2f(m_run - mnew);
        l_run *= resc;
#pragma unroll
        for (int e = 0; e < 16; ++e) { oacc0[e] *= resc; oacc1[e] *= resc; }
        m_run = mnew;
      }
      float rs = 0.0f;
      unsigned pw[8];
#pragma unroll
      for (int u = 0; u < 8; ++u) {
        float p0 = exp2f(st[2 * u] - m_run);
        float p1 = exp2f(st[2 * u + 1] - m_run);
        rs += p0 + p1;
        pw[u] = cvt_pk_bf16(p0, p1);
      }
      rs += __shfl_xor(rs, 32);
      l_run += rs;

#pragma unroll
      for (int c = 0; c < 2; ++c) {
        unsigned w2, w0, w3, w1;
        swap32(pw[c * 4 + 2], pw[c * 4 + 0], hi, w2, w0);
        swap32(pw[c * 4 + 3], pw[c * 4 + 1], hi, w3, w1);
        union { unsigned u[4]; bf16x8 v; } pa;
        pa.u[0] = w0; pa.u[1] = w1; pa.u[2] = w2; pa.u[3] = w3;
        int kb0 = s * 8 + c * 4 + hi * 2;
        int dbl = l31 >> 4;
        int cc8 = (l31 & 15) * 4;
        const bf16_t* p00 = Vs + (kb0 * 4 + dbl) * 64 + cc8;
        const bf16_t* p01 = Vs + ((kb0 + 1) * 4 + dbl) * 64 + cc8;
        const bf16_t* p10 = Vs + (kb0 * 4 + 2 + dbl) * 64 + cc8;
        const bf16_t* p11 = Vs + ((kb0 + 1) * 4 + 2 + dbl) * 64 + cc8;
        s16x4 t00 = tr_b16(p00), t01 = tr_b16(p01);
        s16x4 t10 = tr_b16(p10), t11 = tr_b16(p11);
        asm volatile("s_waitcnt lgkmcnt(0)" ::: "memory");
        __builtin_amdgcn_sched_barrier(0);
        union { s16x4 s4[2]; bf16x8 v; } vf0, vf1;
        vf0.s4[0] = t00; vf0.s4[1] = t01;
        vf1.s4[0] = t10; vf1.s4[1] = t11;
        oacc0 = MFMA32(pa.v, vf0.v, oacc0);
        oacc1 = MFMA32(pa.v, vf1.v, oacc1);
      }
    }
  }

  float linv = 1.0f / l_run;
#pragma unroll
  for (int r = 0; r < 16; ++r) {
    int qrw = (r & 3) + 8 * (r >> 2) + 4 * hi;
    float li = __shfl(linv, qrw);
    size_t orow = (size_t)(qrow_blk + w * 32 + qrw) * 2048 + h * 64 + l31;
    O[orow]      = (bf16_t)(oacc0[r] * li);
    O[orow + 32] = (bf16_t)(oacc1[r] * li);
  }
}

extern "C" void kernel_launch(void* const* d_in, const int* in_sizes, int n_in,
                              void* d_out, int out_size, void* d_ws, size_t ws_size,
                              hipStream_t stream) {
  const float* X  = (const float*)d_in[0];
  const float* Wq = (const float*)d_in[1];
  const float* Wk = (const float*)d_in[2];
  const float* Wv = (const float*)d_in[3];
  const float* Wo = (const float*)d_in[4];
  float* out = (float*)d_out;

  char* ws = (char*)d_ws;
  const size_t MB = 1024 * 1024;
  bf16_t* Xb  = (bf16_t*)(ws + 0);
  bf16_t* WqT = (bf16_t*)(ws + 32 * MB);
  bf16_t* WkT = (bf16_t*)(ws + 40 * MB);
  bf16_t* WvT = (bf16_t*)(ws + 42 * MB);
  bf16_t* WoT = (bf16_t*)(ws + 44 * MB);
  bf16_t* Qp  = (bf16_t*)(ws + 52 * MB);
  bf16_t* Kp  = (bf16_t*)(ws + 84 * MB);
  bf16_t* Vp  = (bf16_t*)(ws + 92 * MB);
  bf16_t* Ob  = (bf16_t*)(ws + 100 * MB);

  // allow 128 KB dynamic LDS for the 8-phase GEMM (host-side, capture-safe)
  hipFuncSetAttribute(reinterpret_cast<const void*>(&k_gemm8<0>),
                      hipFuncAttributeMaxDynamicSharedMemorySize, 131072);
  hipFuncSetAttribute(reinterpret_cast<const void*>(&k_gemm8<1>),
                      hipFuncAttributeMaxDynamicSharedMemorySize, 131072);

  k_convert<<<16384, 256, 0, stream>>>(X, Xb, 4194304);
  k_transpose<<<dim3(32, 32), 256, 0, stream>>>(Wq, WqT, 2048, 2048);
  k_transpose<<<dim3(8, 32), 256, 0, stream>>>(Wk, WkT, 2048, 512);
  k_transpose<<<dim3(8, 32), 256, 0, stream>>>(Wv, WvT, 2048, 512);
  k_transpose<<<dim3(32, 32), 256, 0, stream>>>(Wo, WoT, 2048, 2048);

  k_gemm8<0><<<384, 512, 131072, stream>>>(Xb, WqT, WkT, WvT, Qp, Kp, Vp, nullptr);
  k_attn<<<2048, 256, 0, stream>>>(Qp, Kp, Vp, Ob);
  k_gemm8<1><<<256, 512, 131072, stream>>>(Ob, WoT, nullptr, nullptr, nullptr,
                                           nullptr, nullptr, out);
}